// Round 8
// baseline (301.896 us; speedup 1.0000x reference)
//
#include <hip/hip_runtime.h>
#include <hip/hip_bf16.h>
#include <math.h>

// Problem constants: N=8, L=1024, D=1024, H=16, hd=64, SCALE=0.125
typedef short bf16x8 __attribute__((ext_vector_type(8)));
typedef float f32x4 __attribute__((ext_vector_type(4)));

__device__ __forceinline__ short f2bf(float f) {
  unsigned u = __float_as_uint(f);
  u += 0x7fffu + ((u >> 16) & 1u);          // RNE
  return (short)(u >> 16);
}
__device__ __forceinline__ float bf2f(short h) {
  return __uint_as_float(((unsigned)(unsigned short)h) << 16);
}

typedef __attribute__((address_space(1))) void glob_void;
typedef __attribute__((address_space(3))) void lds_void;
// async global->LDS, 16B per lane; LDS dest = wave-uniform base + lane*16
__device__ __forceinline__ void async16(const void* g, void* l) {
  __builtin_amdgcn_global_load_lds((glob_void*)(uintptr_t)g,
                                   (lds_void*)(unsigned int)(uintptr_t)l,
                                   16, 0, 0);
}

// ---------------- fp32 -> bf16 conversion of x, W_in, W_out ----------------
__global__ void convert3(const float* __restrict__ a, short* __restrict__ ab, int na4,
                         const float* __restrict__ b, short* __restrict__ bb, int nb4,
                         const float* __restrict__ c, short* __restrict__ cb, int nc4) {
  int tid = blockIdx.x * blockDim.x + threadIdx.x;
  int stride = gridDim.x * blockDim.x;
  for (int i = tid; i < na4; i += stride) {
    float4 v = ((const float4*)a)[i];
    ((short4*)ab)[i] = make_short4(f2bf(v.x), f2bf(v.y), f2bf(v.z), f2bf(v.w));
  }
  for (int i = tid; i < nb4; i += stride) {
    float4 v = ((const float4*)b)[i];
    ((short4*)bb)[i] = make_short4(f2bf(v.x), f2bf(v.y), f2bf(v.z), f2bf(v.w));
  }
  for (int i = tid; i < nc4; i += stride) {
    float4 v = ((const float4*)c)[i];
    ((short4*)cb)[i] = make_short4(f2bf(v.x), f2bf(v.y), f2bf(v.z), f2bf(v.w));
  }
}

// ---------------- m97-style B^T GEMM, 2-phase pipelined ---------------------
// C[m][n] = sum_k A[m][k]*B[n][k] + bias[n].
// R7: stage->barrier->compute paid full staging latency every K-step (2150
// cy/step vs 620 cy MFMA; FETCH already at partition floor, so it's latency
// not locality). Fix = flash_attn's proven 2-phase: double-buffered LDS,
// prefetch(t+1) issued BEFORE compute(t), ONE syncthreads per step (its
// implicit vmcnt(0) drains the prefetch). LDS 64KB -> still 2 blocks/CU.
// XCD-chunked swizzle kept (neutral, zero cost). Requires nwg % 8 == 0.
__global__ __launch_bounds__(256, 2) void gemm_bt(
    const short* __restrict__ A, const short* __restrict__ B,
    const float* __restrict__ bias, float* __restrict__ Cf, short* __restrict__ Cb,
    int M, int N, int K) {
  __shared__ short As[2][128 * 64];
  __shared__ short Bs[2][128 * 64];
  const int tid = threadIdx.x;
  const int lane = tid & 63, wave = tid >> 6;
  const int wm = (wave & 1) * 64, wn = (wave >> 1) * 64;
  const int lrow = lane & 15, lgrp = lane >> 4;
  const int xtiles = N >> 7;            // n-tiles per row of the grid
  const int bid = blockIdx.x;
  const int cpx = gridDim.x >> 3;       // chunk per XCD
  const int swz = (bid & 7) * cpx + (bid >> 3);
  const int m0 = (swz / xtiles) * 128, n0 = (swz % xtiles) * 128;
  f32x4 acc[4][4] = {};

  const int srow = tid >> 3;                         // 0..31
  const int schunk = ((tid & 7) ^ (srow & 7)) * 8;   // swizzled source chunk (elems)
  const short* Ag = A + (size_t)(m0 + srow) * K + schunk;
  const short* Bg = B + (size_t)(n0 + srow) * K + schunk;

  auto stage = [&](int k0, int buf) {
#pragma unroll
    for (int r = 0; r < 4; ++r) {
      async16(Ag + (size_t)(32 * r) * K + k0, &As[buf][tid * 8 + r * 2048]);
      async16(Bg + (size_t)(32 * r) * K + k0, &Bs[buf][tid * 8 + r * 2048]);
    }
  };

  stage(0, 0);
  __syncthreads();
  const int nsteps = K >> 6;
  for (int s = 0; s < nsteps; ++s) {
    const int cur = s & 1;
    if (s + 1 < nsteps) stage((s + 1) * 64, cur ^ 1);  // prefetch before compute
#pragma unroll
    for (int kk = 0; kk < 2; ++kk) {
      bf16x8 af[4], bfr[4];
#pragma unroll
      for (int i = 0; i < 4; ++i) {
        const int ra = wm + i * 16 + lrow;
        af[i] = *(const bf16x8*)&As[cur][ra * 64 + (((kk * 4 + lgrp) ^ (ra & 7)) * 8)];
        const int rb = wn + i * 16 + lrow;
        bfr[i] = *(const bf16x8*)&Bs[cur][rb * 64 + (((kk * 4 + lgrp) ^ (rb & 7)) * 8)];
      }
#pragma unroll
      for (int i = 0; i < 4; ++i)
#pragma unroll
        for (int j = 0; j < 4; ++j)
          acc[i][j] = __builtin_amdgcn_mfma_f32_16x16x32_bf16(af[i], bfr[j], acc[i][j], 0, 0, 0);
    }
    __syncthreads();                    // drains prefetch vmcnt + buffer swap
  }
#pragma unroll
  for (int j = 0; j < 4; ++j) {
    const int col = n0 + wn + j * 16 + lrow;
    const float bs = bias[col];
#pragma unroll
    for (int i = 0; i < 4; ++i) {
      const int rb = m0 + wm + i * 16 + lgrp * 4;
#pragma unroll
      for (int r = 0; r < 4; ++r) {
        const float v = acc[i][j][r] + bs;
        if (Cf) Cf[(size_t)(rb + r) * N + col] = v;
        else    Cb[(size_t)(rb + r) * N + col] = f2bf(v);
      }
    }
  }
}

// ---------------- RoPE + head-split + V transpose ----------------
__global__ __launch_bounds__(256) void rope_kernel(
    const short* __restrict__ qkv, short* __restrict__ qh,
    short* __restrict__ kh, short* __restrict__ vt) {
  __shared__ short vtile[64 * 65];
  const int l0 = blockIdx.x * 64, h = blockIdx.y, n = blockIdx.z;
  const int tid = threadIdx.x;
  const int d = tid & 63, lo = tid >> 6;
  const int j = d & 31;
  const float invf = exp2f(-0.4152410118609203f * (float)j);  // 10000^(-j/32)
  const float sgn = (d < 32) ? -1.0f : 1.0f;
  const int po = ((d + 32) & 63) - d;  // pair offset for rotate_half
  const size_t hb = (size_t)(n * 16 + h) * 1024;
#pragma unroll
  for (int i = 0; i < 16; ++i) {
    const int l = l0 + lo + i * 4;
    const short* row = qkv + (size_t)(n * 1024 + l) * 3072 + h * 64;
    const float qv = bf2f(row[d]),        qp = bf2f(row[d + po]);
    const float kv = bf2f(row[1024 + d]), kp = bf2f(row[1024 + d + po]);
    const float vv = bf2f(row[2048 + d]);
    float s, c;
    sincosf((float)l * invf, &s, &c);
    qh[(hb + l) * 64 + d] = f2bf((qv * c + sgn * qp * s) * 0.125f);
    kh[(hb + l) * 64 + d] = f2bf(kv * c + sgn * kp * s);
    vtile[d * 65 + lo + i * 4] = f2bf(vv);
  }
  __syncthreads();
#pragma unroll
  for (int i = 0; i < 16; ++i) {
    const int dd = lo + i * 4;
    vt[hb * 64 + (size_t)dd * 1024 + l0 + d] = vtile[dd * 65 + d];
  }
}

// ---------------- flash attention v2: 2-phase pipelined ---------------------
// block = (n, h, 128 q-rows), 256 thr / 4 waves; wave owns 32 q end-to-end.
// Double-buffered K/V, stage(t+1) issued BEFORE compute(t), ONE syncthreads
// per step. S via swapped mfma(K,Q): packed b64 P-stores, 2-reg rsum.
__global__ __launch_bounds__(256, 3) void flash_attn(
    const short* __restrict__ qh, const short* __restrict__ kh,
    const short* __restrict__ vt, short* __restrict__ attn,
    float* __restrict__ denw) {
  __shared__ short Ks[2][64 * 64];
  __shared__ short Vs[2][64 * 64];
  __shared__ short Pl[4][32 * 64];      // per-wave private P tiles
  const int bid = blockIdx.x;
  const int n = bid & 7;                // same n -> same XCD (L2 locality)
  const int h = (bid >> 3) & 15;
  const int q0 = (bid >> 7) * 128;
  const int tid = threadIdx.x;
  const int wave = tid >> 6, lane = tid & 63;
  const int lrow = lane & 15, lgrp = lane >> 4;
  const int woff = wave * 32;
  const size_t hb = (size_t)(n * 16 + h) * 65536;

  // Q fragments, in regs for the whole kernel
  bf16x8 aq[2][2];
#pragma unroll
  for (int i = 0; i < 2; ++i)
#pragma unroll
    for (int kk = 0; kk < 2; ++kk)
      aq[i][kk] = *(const bf16x8*)(qh + hb +
          (size_t)(q0 + woff + 16 * i + lrow) * 64 + kk * 32 + lgrp * 8);

  const int srow = tid >> 3;                         // 0..31
  const int schunk = ((tid & 7) ^ (srow & 7)) * 8;   // swizzled source chunk
  const short* Kg = kh + hb + (size_t)srow * 64 + schunk;
  const short* Vg = vt + hb + (size_t)srow * 1024 + schunk;
  short* Pw = &Pl[wave][0];

  f32x4 osum[2][4] = {};
  float rsum[2] = {0.f, 0.f};

  // prologue: stage tile 0 into buf 0
#pragma unroll
  for (int r = 0; r < 2; ++r) {
    async16(Kg + (size_t)(32 * r) * 64, &Ks[0][tid * 8 + r * 2048]);
    async16(Vg + (size_t)(32 * r) * 1024, &Vs[0][tid * 8 + r * 2048]);
  }
  __syncthreads();

  for (int step = 0; step < 16; ++step) {
    const int cur = step & 1;
    if (step < 15) {                    // issue NEXT tile before compute
      const int k1 = (step + 1) * 64;
#pragma unroll
      for (int r = 0; r < 2; ++r) {
        async16(Kg + (size_t)(k1 + 32 * r) * 64, &Ks[cur ^ 1][tid * 8 + r * 2048]);
        async16(Vg + (size_t)(32 * r) * 1024 + k1, &Vs[cur ^ 1][tid * 8 + r * 2048]);
      }
    }
    // ---- S = K @ Q (swapped): lane holds q=16i+lrow, keys 16nt+lgrp*4+r ----
    f32x4 sacc[2][4] = {};
#pragma unroll
    for (int kk = 0; kk < 2; ++kk)
#pragma unroll
      for (int nt = 0; nt < 4; ++nt) {
        const int rb = nt * 16 + lrow;
        const bf16x8 ak = *(const bf16x8*)&Ks[cur][rb * 64 + (((kk * 4 + lgrp) ^ (rb & 7)) * 8)];
#pragma unroll
        for (int i = 0; i < 2; ++i)
          sacc[i][nt] = __builtin_amdgcn_mfma_f32_16x16x32_bf16(ak, aq[i][kk], sacc[i][nt], 0, 0, 0);
      }
    // ---- exp, rowsum, packed P store (4 consecutive keys per b64) ----
#pragma unroll
    for (int i = 0; i < 2; ++i)
#pragma unroll
      for (int nt = 0; nt < 4; ++nt) {
        float e0 = __expf(sacc[i][nt][0]), e1 = __expf(sacc[i][nt][1]);
        float e2 = __expf(sacc[i][nt][2]), e3 = __expf(sacc[i][nt][3]);
        rsum[i] += (e0 + e1) + (e2 + e3);
        short4 pk = make_short4(f2bf(e0), f2bf(e1), f2bf(e2), f2bf(e3));
        const int prow = 16 * i + lrow;
        const int cb = 16 * nt + lgrp * 4;
        *(short4*)&Pw[prow * 64 + ((((cb >> 3) ^ (prow & 7))) << 3) + (cb & 7)] = pk;
      }
    // ---- PV: O += P @ V ----
#pragma unroll
    for (int kk = 0; kk < 2; ++kk) {
      bf16x8 pa[2], bv[4];
#pragma unroll
      for (int i = 0; i < 2; ++i) {
        const int ra = 16 * i + lrow;
        pa[i] = *(const bf16x8*)&Pw[ra * 64 + (((kk * 4 + lgrp) ^ (ra & 7)) * 8)];
      }
#pragma unroll
      for (int j = 0; j < 4; ++j) {
        const int rb = 16 * j + lrow;
        bv[j] = *(const bf16x8*)&Vs[cur][rb * 64 + (((kk * 4 + lgrp) ^ (rb & 7)) * 8)];
      }
#pragma unroll
      for (int i = 0; i < 2; ++i)
#pragma unroll
        for (int j = 0; j < 4; ++j)
          osum[i][j] = __builtin_amdgcn_mfma_f32_16x16x32_bf16(pa[i], bv[j], osum[i][j], 0, 0, 0);
    }
    __syncthreads();                    // drains prefetch vmcnt + buffer swap
  }
  // ---- rowsum reduce across lgrp (key partition); q = 16i+lrow ----
#pragma unroll
  for (int t = 0; t < 2; ++t) {
    rsum[t] += __shfl_xor(rsum[t], 16, 64);
    rsum[t] += __shfl_xor(rsum[t], 32, 64);
  }
  const float invq0 = 1.0f / rsum[0], invq1 = 1.0f / rsum[1];
  if (lgrp == 0) {
    denw[(size_t)(n * 16 + h) * 1024 + q0 + woff + lrow] = invq0;
    denw[(size_t)(n * 16 + h) * 1024 + q0 + woff + 16 + lrow] = invq1;
  }
  // redistribute: C-layout row lgrp*4+r needs inv held at lane lgrp*4+r
  float inv8[8];
#pragma unroll
  for (int r = 0; r < 4; ++r) {
    inv8[r] = __shfl(invq0, lgrp * 4 + r, 64);
    inv8[4 + r] = __shfl(invq1, lgrp * 4 + r, 64);
  }
#pragma unroll
  for (int i = 0; i < 2; ++i)
#pragma unroll
    for (int j = 0; j < 4; ++j)
#pragma unroll
      for (int r = 0; r < 4; ++r) {
        const int row = q0 + woff + 16 * i + lgrp * 4 + r;
        attn[(size_t)(n * 1024 + row) * 1024 + h * 64 + 16 * j + lrow] =
            f2bf(osum[i][j][r] * inv8[i * 4 + r]);
      }
}

// ---------------- out2 v2 = mean over heads of softmax(S), pipelined --------
// block = (n, 128 q-rows, 64-key strip), 256 thr / 4 waves; wave owns 32 q.
// Q (16KB) + K (8KB) staged via async16, double-buffered across heads,
// ONE barrier per head. acc over 16 heads in regs, single coalesced write.
__global__ __launch_bounds__(256, 3) void out2_kernel(
    const short* __restrict__ qh, const short* __restrict__ kh,
    const float* __restrict__ denw, float* __restrict__ out2) {
  __shared__ short Qs[2][128 * 64];
  __shared__ short Ks[2][64 * 64];
  const int bid = blockIdx.x;
  const int n = bid & 7;
  const int qt = (bid >> 3) & 7;
  const int kvs = bid >> 6;             // 0..15
  const int q0 = qt * 128, c0 = kvs * 64;
  const int tid = threadIdx.x;
  const int wave = tid >> 6, lane = tid & 63;
  const int lrow = lane & 15, lgrp = lane >> 4;
  const int woff = wave * 32;

  const int srow = tid >> 3;
  const int schunk = ((tid & 7) ^ (srow & 7)) * 8;

  f32x4 acc[2][4] = {};

  // stage head hh's Q+K tiles into buf
  auto stage = [&](int hh, int buf) {
    const size_t hb = (size_t)(n * 16 + hh) * 65536;
#pragma unroll
    for (int r = 0; r < 4; ++r)
      async16(qh + hb + (size_t)(q0 + 32 * r + srow) * 64 + schunk,
              &Qs[buf][tid * 8 + r * 2048]);
#pragma unroll
    for (int r = 0; r < 2; ++r)
      async16(kh + hb + (size_t)(c0 + 32 * r + srow) * 64 + schunk,
              &Ks[buf][tid * 8 + r * 2048]);
  };

  stage(0, 0);
  __syncthreads();
  for (int h = 0; h < 16; ++h) {
    const int cur = h & 1;
    // denw loads first: global, independent -> overlap with MFMAs below
    float invv[8];
#pragma unroll
    for (int i = 0; i < 2; ++i)
#pragma unroll
      for (int r = 0; r < 4; ++r)
        invv[i * 4 + r] =
            denw[(size_t)(n * 16 + h) * 1024 + q0 + woff + 16 * i + lgrp * 4 + r];
    if (h < 15) stage(h + 1, cur ^ 1);
    bf16x8 aq[2][2];
#pragma unroll
    for (int i = 0; i < 2; ++i)
#pragma unroll
      for (int kk = 0; kk < 2; ++kk) {
        const int ra = woff + 16 * i + lrow;
        aq[i][kk] = *(const bf16x8*)&Qs[cur][ra * 64 + (((kk * 4 + lgrp) ^ (ra & 7)) * 8)];
      }
    f32x4 sacc[2][4] = {};
#pragma unroll
    for (int kk = 0; kk < 2; ++kk)
#pragma unroll
      for (int nt = 0; nt < 4; ++nt) {
        const int rb = nt * 16 + lrow;
        const bf16x8 bk = *(const bf16x8*)&Ks[cur][rb * 64 + (((kk * 4 + lgrp) ^ (rb & 7)) * 8)];
#pragma unroll
        for (int i = 0; i < 2; ++i)
          sacc[i][nt] = __builtin_amdgcn_mfma_f32_16x16x32_bf16(aq[i][kk], bk, sacc[i][nt], 0, 0, 0);
      }
#pragma unroll
    for (int i = 0; i < 2; ++i)
#pragma unroll
      for (int nt = 0; nt < 4; ++nt)
#pragma unroll
        for (int r = 0; r < 4; ++r)
          acc[i][nt][r] += __expf(sacc[i][nt][r]) * invv[i * 4 + r];
    __syncthreads();
  }
#pragma unroll
  for (int i = 0; i < 2; ++i)
#pragma unroll
    for (int nt = 0; nt < 4; ++nt)
#pragma unroll
      for (int r = 0; r < 4; ++r) {
        const int row = q0 + woff + 16 * i + lgrp * 4 + r;
        out2[(size_t)(n * 1024 + row) * 1024 + c0 + 16 * nt + lrow] = acc[i][nt][r] * 0.0625f;
      }
}

extern "C" void kernel_launch(void* const* d_in, const int* in_sizes, int n_in,
                              void* d_out, int out_size, void* d_ws, size_t ws_size,
                              hipStream_t stream) {
  const float* x  = (const float*)d_in[0];   // (8,1024,1024)
  const float* Wi = (const float*)d_in[1];   // (3072,1024)
  const float* bi = (const float*)d_in[2];   // (3072,)
  const float* Wo = (const float*)d_in[3];   // (1024,1024)
  const float* bo = (const float*)d_in[4];   // (1024,)
  float* out  = (float*)d_out;                       // (8,1024,1024)
  float* out2 = out + (size_t)8 * 1024 * 1024;       // (8,1024,1024) mean attn

  char* p = (char*)d_ws;
  short* xb  = (short*)p; p += (size_t)8388608 * 2;   // x bf16 (reused as attn later)
  short* wb  = (short*)p; p += (size_t)3145728 * 2;   // W_in bf16
  short* wob = (short*)p; p += (size_t)1048576 * 2;   // W_out bf16
  short* qkv = (short*)p; p += (size_t)8 * 1024 * 3072 * 2;  // 50.3 MB (dead after rope)
  short* qh  = (short*)p; p += (size_t)8388608 * 2;   // (n,h,l,d) bf16, pre-scaled
  short* kh  = (short*)p; p += (size_t)8388608 * 2;   // (n,h,l,d) bf16
  short* vt  = (short*)p; p += (size_t)8388608 * 2;   // (n,h,d,l) bf16
  float* denw = (float*)p; p += (size_t)131072 * 4;   // inv softmax denominators
  short* attn = xb;  // xb dead after gemm_qkv

  convert3<<<2048, 256, 0, stream>>>(x, xb, 8388608 / 4, Wi, wb, 3145728 / 4,
                                     Wo, wob, 1048576 / 4);
  gemm_bt<<<1536, 256, 0, stream>>>(xb, wb, bi, nullptr, qkv, 8192, 3072, 1024);
  rope_kernel<<<dim3(16, 16, 8), 256, 0, stream>>>(qkv, qh, kh, vt);
  flash_attn<<<1024, 256, 0, stream>>>(qh, kh, vt, attn, denw);
  out2_kernel<<<1024, 256, 0, stream>>>(qh, kh, denw, out2);
  gemm_bt<<<512, 256, 0, stream>>>(attn, wob, bo, out, nullptr, 8192, 1024, 1024);
}

// Round 9
// 270.623 us; speedup vs baseline: 1.1156x; 1.1156x over previous
//
#include <hip/hip_runtime.h>
#include <hip/hip_bf16.h>
#include <math.h>

// Problem constants: N=8, L=1024, D=1024, H=16, hd=64, SCALE=0.125
typedef short bf16x8 __attribute__((ext_vector_type(8)));
typedef float f32x4 __attribute__((ext_vector_type(4)));

__device__ __forceinline__ short f2bf(float f) {
  unsigned u = __float_as_uint(f);
  u += 0x7fffu + ((u >> 16) & 1u);          // RNE
  return (short)(u >> 16);
}
__device__ __forceinline__ float bf2f(short h) {
  return __uint_as_float(((unsigned)(unsigned short)h) << 16);
}

typedef __attribute__((address_space(1))) void glob_void;
typedef __attribute__((address_space(3))) void lds_void;
// async global->LDS, 16B per lane; LDS dest = wave-uniform base + lane*16
__device__ __forceinline__ void async16(const void* g, void* l) {
  __builtin_amdgcn_global_load_lds((glob_void*)(uintptr_t)g,
                                   (lds_void*)(unsigned int)(uintptr_t)l,
                                   16, 0, 0);
}

// -------- fp32 -> bf16 conversion of x, W_in, W_out + RoPE cos/sin table ----
__global__ void convert3(const float* __restrict__ a, short* __restrict__ ab, int na4,
                         const float* __restrict__ b, short* __restrict__ bb, int nb4,
                         const float* __restrict__ c, short* __restrict__ cb, int nc4,
                         float2* __restrict__ rt) {
  int tid = blockIdx.x * blockDim.x + threadIdx.x;
  int stride = gridDim.x * blockDim.x;
  for (int i = tid; i < na4; i += stride) {
    float4 v = ((const float4*)a)[i];
    ((short4*)ab)[i] = make_short4(f2bf(v.x), f2bf(v.y), f2bf(v.z), f2bf(v.w));
  }
  for (int i = tid; i < nb4; i += stride) {
    float4 v = ((const float4*)b)[i];
    ((short4*)bb)[i] = make_short4(f2bf(v.x), f2bf(v.y), f2bf(v.z), f2bf(v.w));
  }
  for (int i = tid; i < nc4; i += stride) {
    float4 v = ((const float4*)c)[i];
    ((short4*)cb)[i] = make_short4(f2bf(v.x), f2bf(v.y), f2bf(v.z), f2bf(v.w));
  }
  // RoPE table: rt[l*32+dj] = (cos, sin)(l * 10000^(-dj/32)), l<1024, dj<32
  for (int i = tid; i < 32768; i += stride) {
    const int l = i >> 5, dj = i & 31;
    float s, cc;
    sincosf((float)l * exp2f(-0.4152410118609203f * (float)dj), &s, &cc);
    rt[i] = make_float2(cc, s);
  }
}

// ---------------- QKV GEMM + fused RoPE/head-split/V-transpose --------------
// C = x @ W_in^T + b_in, then per output category:
//   Q cols (0-1023):    rope (table) * 0.125 -> qh (n,h,l,d)
//   K cols (1024-2047): rope (table)          -> kh (n,h,l,d)
//   V cols (2048-3071): transpose             -> vt (n,h,d,l)
// Rope pairing d<->d+-32 is IN-THREAD: acc[i][j] pairs acc[i][j^2] (cols +-32).
// Thread-held layout (fixed d, varying l) doesn't coalesce for qh/vt, so the
// epilogue bounces through the dead 64KB staging LDS with chunk-XOR swizzle
// (conflict-free b128 reads) then writes fully-coalesced 1KB/wave stores.
// Main loop = proven 2-phase double-buffered pipeline (R8: 68us, 31% Mfma).
__global__ __launch_bounds__(256, 2) void gemm_qkv(
    const short* __restrict__ A, const short* __restrict__ B,
    const float* __restrict__ bias, const float2* __restrict__ rt,
    short* __restrict__ qh, short* __restrict__ kh, short* __restrict__ vt) {
  __shared__ short smem[32768];         // main loop: As/Bs dbuf; epilogue: tile
  const int K = 1024, xtiles = 24;
  const int tid = threadIdx.x;
  const int lane = tid & 63, wave = tid >> 6;
  const int wm = (wave & 1) * 64, wn = (wave >> 1) * 64;
  const int lrow = lane & 15, lgrp = lane >> 4;
  const int bid = blockIdx.x;
  const int cpx = gridDim.x >> 3;       // XCD-chunked swizzle (nwg%8==0)
  const int swz = (bid & 7) * cpx + (bid >> 3);
  const int m0 = (swz / xtiles) * 128, n0 = (swz % xtiles) * 128;
  f32x4 acc[4][4] = {};

  const int srow = tid >> 3;                         // 0..31
  const int schunk = ((tid & 7) ^ (srow & 7)) * 8;   // swizzled source chunk
  const short* Ag = A + (size_t)(m0 + srow) * K + schunk;
  const short* Bg = B + (size_t)(n0 + srow) * K + schunk;
  short* As = smem;                     // [2][8192]
  short* Bs = smem + 16384;             // [2][8192]

  auto stage = [&](int k0, int buf) {
#pragma unroll
    for (int r = 0; r < 4; ++r) {
      async16(Ag + (size_t)(32 * r) * K + k0, &As[buf * 8192 + tid * 8 + r * 2048]);
      async16(Bg + (size_t)(32 * r) * K + k0, &Bs[buf * 8192 + tid * 8 + r * 2048]);
    }
  };

  stage(0, 0);
  __syncthreads();
  for (int s = 0; s < 16; ++s) {
    const int cur = s & 1;
    if (s < 15) stage((s + 1) * 64, cur ^ 1);  // prefetch before compute
#pragma unroll
    for (int kk = 0; kk < 2; ++kk) {
      bf16x8 af[4], bfr[4];
#pragma unroll
      for (int i = 0; i < 4; ++i) {
        const int ra = wm + i * 16 + lrow;
        af[i] = *(const bf16x8*)&As[cur * 8192 + ra * 64 + (((kk * 4 + lgrp) ^ (ra & 7)) * 8)];
        const int rb = wn + i * 16 + lrow;
        bfr[i] = *(const bf16x8*)&Bs[cur * 8192 + rb * 64 + (((kk * 4 + lgrp) ^ (rb & 7)) * 8)];
      }
#pragma unroll
      for (int i = 0; i < 4; ++i)
#pragma unroll
        for (int j = 0; j < 4; ++j)
          acc[i][j] = __builtin_amdgcn_mfma_f32_16x16x32_bf16(af[i], bfr[j], acc[i][j], 0, 0, 0);
    }
    __syncthreads();                    // drains prefetch vmcnt + buffer swap
  }

  // ---------------- fused epilogue ----------------
  const int cat = n0 >> 10;             // 0=Q, 1=K, 2=V
  const int c0 = n0 & 1023;             // col base within category
  const int nb = m0 >> 10;              // batch index
  const int l0 = m0 & 1023;             // sequence base
  const size_t hbase = ((size_t)nb * 16 + (c0 >> 6)) * 65536;
  float bs[4];
#pragma unroll
  for (int j = 0; j < 4; ++j) bs[j] = bias[n0 + wn + j * 16 + lrow];

  if (cat < 2) {
    // -------- Q / K: rope -> tile[(hh*128+lrel)][d], chunk-XOR swizzled -----
    const float scl = (cat == 0) ? 0.125f : 1.0f;
    float2 cs[4][4][2];                 // cos/sin per (i, r, p= d<32 half)
#pragma unroll
    for (int i = 0; i < 4; ++i)
#pragma unroll
      for (int r = 0; r < 4; ++r) {
        const int lg = l0 + wm + i * 16 + lgrp * 4 + r;
        cs[i][r][0] = rt[lg * 32 + lrow];
        cs[i][r][1] = rt[lg * 32 + 16 + lrow];
      }
#pragma unroll
    for (int i = 0; i < 4; ++i)
#pragma unroll
      for (int j = 0; j < 4; ++j) {
        const int hh = (wn + j * 16 + lrow) >> 6;  // head half (0/1)
        const int din = (j * 16 + lrow) & 63;      // d within head
        const float sgn = (j & 2) ? 1.0f : -1.0f;  // d<32 -> -pair
        const int p = j & 1;
#pragma unroll
        for (int r = 0; r < 4; ++r) {
          const int lrel = wm + i * 16 + lgrp * 4 + r;
          const float v = acc[i][j][r] + bs[j];
          const float vp = acc[i][j ^ 2][r] + bs[j ^ 2];
          const float2 a = cs[i][r][p];
          const float o = (v * a.x + sgn * vp * a.y) * scl;
          const int row = hh * 128 + lrel;
          smem[row * 64 + (((din >> 3) ^ (lrel & 7)) << 3) + (din & 7)] = f2bf(o);
        }
      }
    __syncthreads();
    short* dst = (cat == 0) ? qh : kh;
#pragma unroll
    for (int it = 0; it < 8; ++it) {
      const int row = it * 32 + wave * 8 + (lane >> 3);
      const int c = lane & 7;
      const int hh = row >> 7, lrel = row & 127;
      const bf16x8 v = *(const bf16x8*)&smem[row * 64 + ((c ^ (row & 7)) << 3)];
      *(bf16x8*)&dst[hbase + (size_t)hh * 65536 + (size_t)(l0 + lrel) * 64 + c * 8] = v;
    }
  } else {
    // -------- V: transpose -> tile[d][l], chunk-XOR swizzled ----------------
#pragma unroll
    for (int i = 0; i < 4; ++i)
#pragma unroll
      for (int j = 0; j < 4; ++j) {
        const int dt = wn + j * 16 + lrow;         // 0..127 (2 heads x 64 d)
        const int lb = wm + i * 16 + lgrp * 4;     // 4-aligned l base
        short4 pk;
        pk.x = f2bf(acc[i][j][0] + bs[j]); pk.y = f2bf(acc[i][j][1] + bs[j]);
        pk.z = f2bf(acc[i][j][2] + bs[j]); pk.w = f2bf(acc[i][j][3] + bs[j]);
        *(short4*)&smem[dt * 128 + ((((lb >> 3) ^ (dt & 7)) << 3) | (lb & 7))] = pk;
      }
    __syncthreads();
#pragma unroll
    for (int it = 0; it < 8; ++it) {
      const int row = it * 16 + wave * 4 + (lane >> 4);  // d_tile 0..127
      const int c = lane & 15;                           // l chunk
      const int cx = (c & 8) | ((c & 7) ^ (row & 7));
      const bf16x8 v = *(const bf16x8*)&smem[row * 128 + (cx << 3)];
      const int hh = row >> 6, d = row & 63;
      *(bf16x8*)&vt[hbase + (size_t)hh * 65536 + (size_t)d * 1024 + l0 + c * 8] = v;
    }
  }
}

// ---------------- m97-style B^T GEMM, 2-phase pipelined (proj) --------------
__global__ __launch_bounds__(256, 2) void gemm_bt(
    const short* __restrict__ A, const short* __restrict__ B,
    const float* __restrict__ bias, float* __restrict__ Cf,
    int M, int N, int K) {
  __shared__ short As[2][128 * 64];
  __shared__ short Bs[2][128 * 64];
  const int tid = threadIdx.x;
  const int lane = tid & 63, wave = tid >> 6;
  const int wm = (wave & 1) * 64, wn = (wave >> 1) * 64;
  const int lrow = lane & 15, lgrp = lane >> 4;
  const int xtiles = N >> 7;
  const int bid = blockIdx.x;
  const int cpx = gridDim.x >> 3;
  const int swz = (bid & 7) * cpx + (bid >> 3);
  const int m0 = (swz / xtiles) * 128, n0 = (swz % xtiles) * 128;
  f32x4 acc[4][4] = {};

  const int srow = tid >> 3;
  const int schunk = ((tid & 7) ^ (srow & 7)) * 8;
  const short* Ag = A + (size_t)(m0 + srow) * K + schunk;
  const short* Bg = B + (size_t)(n0 + srow) * K + schunk;

  auto stage = [&](int k0, int buf) {
#pragma unroll
    for (int r = 0; r < 4; ++r) {
      async16(Ag + (size_t)(32 * r) * K + k0, &As[buf][tid * 8 + r * 2048]);
      async16(Bg + (size_t)(32 * r) * K + k0, &Bs[buf][tid * 8 + r * 2048]);
    }
  };

  stage(0, 0);
  __syncthreads();
  const int nsteps = K >> 6;
  for (int s = 0; s < nsteps; ++s) {
    const int cur = s & 1;
    if (s + 1 < nsteps) stage((s + 1) * 64, cur ^ 1);
#pragma unroll
    for (int kk = 0; kk < 2; ++kk) {
      bf16x8 af[4], bfr[4];
#pragma unroll
      for (int i = 0; i < 4; ++i) {
        const int ra = wm + i * 16 + lrow;
        af[i] = *(const bf16x8*)&As[cur][ra * 64 + (((kk * 4 + lgrp) ^ (ra & 7)) * 8)];
        const int rb = wn + i * 16 + lrow;
        bfr[i] = *(const bf16x8*)&Bs[cur][rb * 64 + (((kk * 4 + lgrp) ^ (rb & 7)) * 8)];
      }
#pragma unroll
      for (int i = 0; i < 4; ++i)
#pragma unroll
        for (int j = 0; j < 4; ++j)
          acc[i][j] = __builtin_amdgcn_mfma_f32_16x16x32_bf16(af[i], bfr[j], acc[i][j], 0, 0, 0);
    }
    __syncthreads();
  }
#pragma unroll
  for (int j = 0; j < 4; ++j) {
    const int col = n0 + wn + j * 16 + lrow;
    const float bsv = bias[col];
#pragma unroll
    for (int i = 0; i < 4; ++i) {
      const int rb = m0 + wm + i * 16 + lgrp * 4;
#pragma unroll
      for (int r = 0; r < 4; ++r)
        Cf[(size_t)(rb + r) * N + col] = acc[i][j][r] + bsv;
    }
  }
}

// ---------------- flash attention v2: 2-phase pipelined ---------------------
// block = (n, h, 128 q-rows), 256 thr / 4 waves; wave owns 32 q end-to-end.
// Double-buffered K/V, stage(t+1) issued BEFORE compute(t), ONE syncthreads
// per step. S via swapped mfma(K,Q): packed b64 P-stores, 2-reg rsum.
__global__ __launch_bounds__(256, 3) void flash_attn(
    const short* __restrict__ qh, const short* __restrict__ kh,
    const short* __restrict__ vt, short* __restrict__ attn,
    float* __restrict__ denw) {
  __shared__ short Ks[2][64 * 64];
  __shared__ short Vs[2][64 * 64];
  __shared__ short Pl[4][32 * 64];      // per-wave private P tiles
  const int bid = blockIdx.x;
  const int n = bid & 7;                // same n -> same XCD (L2 locality)
  const int h = (bid >> 3) & 15;
  const int q0 = (bid >> 7) * 128;
  const int tid = threadIdx.x;
  const int wave = tid >> 6, lane = tid & 63;
  const int lrow = lane & 15, lgrp = lane >> 4;
  const int woff = wave * 32;
  const size_t hb = (size_t)(n * 16 + h) * 65536;

  bf16x8 aq[2][2];
#pragma unroll
  for (int i = 0; i < 2; ++i)
#pragma unroll
    for (int kk = 0; kk < 2; ++kk)
      aq[i][kk] = *(const bf16x8*)(qh + hb +
          (size_t)(q0 + woff + 16 * i + lrow) * 64 + kk * 32 + lgrp * 8);

  const int srow = tid >> 3;
  const int schunk = ((tid & 7) ^ (srow & 7)) * 8;
  const short* Kg = kh + hb + (size_t)srow * 64 + schunk;
  const short* Vg = vt + hb + (size_t)srow * 1024 + schunk;
  short* Pw = &Pl[wave][0];

  f32x4 osum[2][4] = {};
  float rsum[2] = {0.f, 0.f};

#pragma unroll
  for (int r = 0; r < 2; ++r) {
    async16(Kg + (size_t)(32 * r) * 64, &Ks[0][tid * 8 + r * 2048]);
    async16(Vg + (size_t)(32 * r) * 1024, &Vs[0][tid * 8 + r * 2048]);
  }
  __syncthreads();

  for (int step = 0; step < 16; ++step) {
    const int cur = step & 1;
    if (step < 15) {
      const int k1 = (step + 1) * 64;
#pragma unroll
      for (int r = 0; r < 2; ++r) {
        async16(Kg + (size_t)(k1 + 32 * r) * 64, &Ks[cur ^ 1][tid * 8 + r * 2048]);
        async16(Vg + (size_t)(32 * r) * 1024 + k1, &Vs[cur ^ 1][tid * 8 + r * 2048]);
      }
    }
    f32x4 sacc[2][4] = {};
#pragma unroll
    for (int kk = 0; kk < 2; ++kk)
#pragma unroll
      for (int nt = 0; nt < 4; ++nt) {
        const int rb = nt * 16 + lrow;
        const bf16x8 ak = *(const bf16x8*)&Ks[cur][rb * 64 + (((kk * 4 + lgrp) ^ (rb & 7)) * 8)];
#pragma unroll
        for (int i = 0; i < 2; ++i)
          sacc[i][nt] = __builtin_amdgcn_mfma_f32_16x16x32_bf16(ak, aq[i][kk], sacc[i][nt], 0, 0, 0);
      }
#pragma unroll
    for (int i = 0; i < 2; ++i)
#pragma unroll
      for (int nt = 0; nt < 4; ++nt) {
        float e0 = __expf(sacc[i][nt][0]), e1 = __expf(sacc[i][nt][1]);
        float e2 = __expf(sacc[i][nt][2]), e3 = __expf(sacc[i][nt][3]);
        rsum[i] += (e0 + e1) + (e2 + e3);
        short4 pk = make_short4(f2bf(e0), f2bf(e1), f2bf(e2), f2bf(e3));
        const int prow = 16 * i + lrow;
        const int cb = 16 * nt + lgrp * 4;
        *(short4*)&Pw[prow * 64 + ((((cb >> 3) ^ (prow & 7))) << 3) + (cb & 7)] = pk;
      }
#pragma unroll
    for (int kk = 0; kk < 2; ++kk) {
      bf16x8 pa[2], bv[4];
#pragma unroll
      for (int i = 0; i < 2; ++i) {
        const int ra = 16 * i + lrow;
        pa[i] = *(const bf16x8*)&Pw[ra * 64 + (((kk * 4 + lgrp) ^ (ra & 7)) * 8)];
      }
#pragma unroll
      for (int j = 0; j < 4; ++j) {
        const int rb = 16 * j + lrow;
        bv[j] = *(const bf16x8*)&Vs[cur][rb * 64 + (((kk * 4 + lgrp) ^ (rb & 7)) * 8)];
      }
#pragma unroll
      for (int i = 0; i < 2; ++i)
#pragma unroll
        for (int j = 0; j < 4; ++j)
          osum[i][j] = __builtin_amdgcn_mfma_f32_16x16x32_bf16(pa[i], bv[j], osum[i][j], 0, 0, 0);
    }
    __syncthreads();
  }
#pragma unroll
  for (int t = 0; t < 2; ++t) {
    rsum[t] += __shfl_xor(rsum[t], 16, 64);
    rsum[t] += __shfl_xor(rsum[t], 32, 64);
  }
  const float invq0 = 1.0f / rsum[0], invq1 = 1.0f / rsum[1];
  if (lgrp == 0) {
    denw[(size_t)(n * 16 + h) * 1024 + q0 + woff + lrow] = invq0;
    denw[(size_t)(n * 16 + h) * 1024 + q0 + woff + 16 + lrow] = invq1;
  }
  float inv8[8];
#pragma unroll
  for (int r = 0; r < 4; ++r) {
    inv8[r] = __shfl(invq0, lgrp * 4 + r, 64);
    inv8[4 + r] = __shfl(invq1, lgrp * 4 + r, 64);
  }
#pragma unroll
  for (int i = 0; i < 2; ++i)
#pragma unroll
    for (int j = 0; j < 4; ++j)
#pragma unroll
      for (int r = 0; r < 4; ++r) {
        const int row = q0 + woff + 16 * i + lgrp * 4 + r;
        attn[(size_t)(n * 1024 + row) * 1024 + h * 64 + 16 * j + lrow] =
            f2bf(osum[i][j][r] * inv8[i * 4 + r]);
      }
}

// ---------------- out2 v2 = mean over heads of softmax(S), pipelined --------
__global__ __launch_bounds__(256, 3) void out2_kernel(
    const short* __restrict__ qh, const short* __restrict__ kh,
    const float* __restrict__ denw, float* __restrict__ out2) {
  __shared__ short Qs[2][128 * 64];
  __shared__ short Ks[2][64 * 64];
  const int bid = blockIdx.x;
  const int n = bid & 7;
  const int qt = (bid >> 3) & 7;
  const int kvs = bid >> 6;
  const int q0 = qt * 128, c0 = kvs * 64;
  const int tid = threadIdx.x;
  const int wave = tid >> 6, lane = tid & 63;
  const int lrow = lane & 15, lgrp = lane >> 4;
  const int woff = wave * 32;

  const int srow = tid >> 3;
  const int schunk = ((tid & 7) ^ (srow & 7)) * 8;

  f32x4 acc[2][4] = {};

  auto stage = [&](int hh, int buf) {
    const size_t hb = (size_t)(n * 16 + hh) * 65536;
#pragma unroll
    for (int r = 0; r < 4; ++r)
      async16(qh + hb + (size_t)(q0 + 32 * r + srow) * 64 + schunk,
              &Qs[buf][tid * 8 + r * 2048]);
#pragma unroll
    for (int r = 0; r < 2; ++r)
      async16(kh + hb + (size_t)(c0 + 32 * r + srow) * 64 + schunk,
              &Ks[buf][tid * 8 + r * 2048]);
  };

  stage(0, 0);
  __syncthreads();
  for (int h = 0; h < 16; ++h) {
    const int cur = h & 1;
    float invv[8];
#pragma unroll
    for (int i = 0; i < 2; ++i)
#pragma unroll
      for (int r = 0; r < 4; ++r)
        invv[i * 4 + r] =
            denw[(size_t)(n * 16 + h) * 1024 + q0 + woff + 16 * i + lgrp * 4 + r];
    if (h < 15) stage(h + 1, cur ^ 1);
    bf16x8 aq[2][2];
#pragma unroll
    for (int i = 0; i < 2; ++i)
#pragma unroll
      for (int kk = 0; kk < 2; ++kk) {
        const int ra = woff + 16 * i + lrow;
        aq[i][kk] = *(const bf16x8*)&Qs[cur][ra * 64 + (((kk * 4 + lgrp) ^ (ra & 7)) * 8)];
      }
    f32x4 sacc[2][4] = {};
#pragma unroll
    for (int kk = 0; kk < 2; ++kk)
#pragma unroll
      for (int nt = 0; nt < 4; ++nt) {
        const int rb = nt * 16 + lrow;
        const bf16x8 bk = *(const bf16x8*)&Ks[cur][rb * 64 + (((kk * 4 + lgrp) ^ (rb & 7)) * 8)];
#pragma unroll
        for (int i = 0; i < 2; ++i)
          sacc[i][nt] = __builtin_amdgcn_mfma_f32_16x16x32_bf16(aq[i][kk], bk, sacc[i][nt], 0, 0, 0);
      }
#pragma unroll
    for (int i = 0; i < 2; ++i)
#pragma unroll
      for (int nt = 0; nt < 4; ++nt)
#pragma unroll
        for (int r = 0; r < 4; ++r)
          acc[i][nt][r] += __expf(sacc[i][nt][r]) * invv[i * 4 + r];
    __syncthreads();
  }
#pragma unroll
  for (int i = 0; i < 2; ++i)
#pragma unroll
    for (int nt = 0; nt < 4; ++nt)
#pragma unroll
      for (int r = 0; r < 4; ++r) {
        const int row = q0 + woff + 16 * i + lgrp * 4 + r;
        out2[(size_t)(n * 1024 + row) * 1024 + c0 + 16 * nt + lrow] = acc[i][nt][r] * 0.0625f;
      }
}

extern "C" void kernel_launch(void* const* d_in, const int* in_sizes, int n_in,
                              void* d_out, int out_size, void* d_ws, size_t ws_size,
                              hipStream_t stream) {
  const float* x  = (const float*)d_in[0];   // (8,1024,1024)
  const float* Wi = (const float*)d_in[1];   // (3072,1024)
  const float* bi = (const float*)d_in[2];   // (3072,)
  const float* Wo = (const float*)d_in[3];   // (1024,1024)
  const float* bo = (const float*)d_in[4];   // (1024,)
  float* out  = (float*)d_out;                       // (8,1024,1024)
  float* out2 = out + (size_t)8 * 1024 * 1024;       // (8,1024,1024) mean attn

  char* p = (char*)d_ws;
  short* xb  = (short*)p; p += (size_t)8388608 * 2;   // x bf16 (reused as attn later)
  short* wb  = (short*)p; p += (size_t)3145728 * 2;   // W_in bf16
  short* wob = (short*)p; p += (size_t)1048576 * 2;   // W_out bf16
  short* qh  = (short*)p; p += (size_t)8388608 * 2;   // (n,h,l,d) bf16, pre-scaled
  short* kh  = (short*)p; p += (size_t)8388608 * 2;   // (n,h,l,d) bf16
  short* vt  = (short*)p; p += (size_t)8388608 * 2;   // (n,h,d,l) bf16
  float* denw = (float*)p; p += (size_t)131072 * 4;   // inv softmax denominators
  float2* ropet = (float2*)p; p += (size_t)32768 * 8; // rope cos/sin table
  short* attn = xb;  // xb dead after gemm_qkv

  convert3<<<2048, 256, 0, stream>>>(x, xb, 8388608 / 4, Wi, wb, 3145728 / 4,
                                     Wo, wob, 1048576 / 4, ropet);
  gemm_qkv<<<1536, 256, 0, stream>>>(xb, wb, bi, ropet, qh, kh, vt);
  flash_attn<<<1024, 256, 0, stream>>>(qh, kh, vt, attn, denw);
  out2_kernel<<<1024, 256, 0, stream>>>(qh, kh, denw, out2);
  gemm_bt<<<512, 256, 0, stream>>>(attn, wob, bo, out, 8192, 1024, 1024);
}

// Round 10
// 264.892 us; speedup vs baseline: 1.1397x; 1.0216x over previous
//
#include <hip/hip_runtime.h>
#include <hip/hip_bf16.h>
#include <math.h>

// Problem constants: N=8, L=1024, D=1024, H=16, hd=64, SCALE=0.125
typedef short bf16x8 __attribute__((ext_vector_type(8)));
typedef float f32x4 __attribute__((ext_vector_type(4)));

__device__ __forceinline__ short f2bf(float f) {
  unsigned u = __float_as_uint(f);
  u += 0x7fffu + ((u >> 16) & 1u);          // RNE
  return (short)(u >> 16);
}
__device__ __forceinline__ float bf2f(short h) {
  return __uint_as_float(((unsigned)(unsigned short)h) << 16);
}

typedef __attribute__((address_space(1))) void glob_void;
typedef __attribute__((address_space(3))) void lds_void;
// async global->LDS, 16B per lane; LDS dest = wave-uniform base + lane*16
__device__ __forceinline__ void async16(const void* g, void* l) {
  __builtin_amdgcn_global_load_lds((glob_void*)(uintptr_t)g,
                                   (lds_void*)(unsigned int)(uintptr_t)l,
                                   16, 0, 0);
}

// -------- fp32 -> bf16 conversion of x, W_in, W_out + RoPE cos/sin table ----
__global__ void convert3(const float* __restrict__ a, short* __restrict__ ab, int na4,
                         const float* __restrict__ b, short* __restrict__ bb, int nb4,
                         const float* __restrict__ c, short* __restrict__ cb, int nc4,
                         float2* __restrict__ rt) {
  int tid = blockIdx.x * blockDim.x + threadIdx.x;
  int stride = gridDim.x * blockDim.x;
  for (int i = tid; i < na4; i += stride) {
    float4 v = ((const float4*)a)[i];
    ((short4*)ab)[i] = make_short4(f2bf(v.x), f2bf(v.y), f2bf(v.z), f2bf(v.w));
  }
  for (int i = tid; i < nb4; i += stride) {
    float4 v = ((const float4*)b)[i];
    ((short4*)bb)[i] = make_short4(f2bf(v.x), f2bf(v.y), f2bf(v.z), f2bf(v.w));
  }
  for (int i = tid; i < nc4; i += stride) {
    float4 v = ((const float4*)c)[i];
    ((short4*)cb)[i] = make_short4(f2bf(v.x), f2bf(v.y), f2bf(v.z), f2bf(v.w));
  }
  // RoPE table: rt[l*32+dj] = (cos, sin)(l * 10000^(-dj/32)), l<1024, dj<32
  for (int i = tid; i < 32768; i += stride) {
    const int l = i >> 5, dj = i & 31;
    float s, cc;
    sincosf((float)l * exp2f(-0.4152410118609203f * (float)dj), &s, &cc);
    rt[i] = make_float2(cc, s);
  }
}

// ---------------- QKV GEMM + fused RoPE/head-split/V-transpose --------------
// C = x @ W_in^T + b_in, then per output category:
//   Q cols (0-1023):    rope (table) * 0.125 -> qh (n,h,l,d)
//   K cols (1024-2047): rope (table)          -> kh (n,h,l,d)
//   V cols (2048-3071): transpose             -> vt (n,h,d,l)
// Rope pairing d<->d+-32 is IN-THREAD: acc[i][j] pairs acc[i][j^2] (cols +-32).
// Epilogue bounces through the dead 64KB staging LDS with chunk-XOR swizzle
// then writes fully-coalesced 1KB/wave stores. (R9: 67.5us, 32% MfmaUtil.)
__global__ __launch_bounds__(256, 2) void gemm_qkv(
    const short* __restrict__ A, const short* __restrict__ B,
    const float* __restrict__ bias, const float2* __restrict__ rt,
    short* __restrict__ qh, short* __restrict__ kh, short* __restrict__ vt) {
  __shared__ short smem[32768];         // main loop: As/Bs dbuf; epilogue: tile
  const int K = 1024, xtiles = 24;
  const int tid = threadIdx.x;
  const int lane = tid & 63, wave = tid >> 6;
  const int wm = (wave & 1) * 64, wn = (wave >> 1) * 64;
  const int lrow = lane & 15, lgrp = lane >> 4;
  const int bid = blockIdx.x;
  const int cpx = gridDim.x >> 3;       // XCD-chunked swizzle (nwg%8==0)
  const int swz = (bid & 7) * cpx + (bid >> 3);
  const int m0 = (swz / xtiles) * 128, n0 = (swz % xtiles) * 128;
  f32x4 acc[4][4] = {};

  const int srow = tid >> 3;                         // 0..31
  const int schunk = ((tid & 7) ^ (srow & 7)) * 8;   // swizzled source chunk
  const short* Ag = A + (size_t)(m0 + srow) * K + schunk;
  const short* Bg = B + (size_t)(n0 + srow) * K + schunk;
  short* As = smem;                     // [2][8192]
  short* Bs = smem + 16384;             // [2][8192]

  auto stage = [&](int k0, int buf) {
#pragma unroll
    for (int r = 0; r < 4; ++r) {
      async16(Ag + (size_t)(32 * r) * K + k0, &As[buf * 8192 + tid * 8 + r * 2048]);
      async16(Bg + (size_t)(32 * r) * K + k0, &Bs[buf * 8192 + tid * 8 + r * 2048]);
    }
  };

  stage(0, 0);
  __syncthreads();
  for (int s = 0; s < 16; ++s) {
    const int cur = s & 1;
    if (s < 15) stage((s + 1) * 64, cur ^ 1);  // prefetch before compute
#pragma unroll
    for (int kk = 0; kk < 2; ++kk) {
      bf16x8 af[4], bfr[4];
#pragma unroll
      for (int i = 0; i < 4; ++i) {
        const int ra = wm + i * 16 + lrow;
        af[i] = *(const bf16x8*)&As[cur * 8192 + ra * 64 + (((kk * 4 + lgrp) ^ (ra & 7)) * 8)];
        const int rb = wn + i * 16 + lrow;
        bfr[i] = *(const bf16x8*)&Bs[cur * 8192 + rb * 64 + (((kk * 4 + lgrp) ^ (rb & 7)) * 8)];
      }
#pragma unroll
      for (int i = 0; i < 4; ++i)
#pragma unroll
        for (int j = 0; j < 4; ++j)
          acc[i][j] = __builtin_amdgcn_mfma_f32_16x16x32_bf16(af[i], bfr[j], acc[i][j], 0, 0, 0);
    }
    __syncthreads();                    // drains prefetch vmcnt + buffer swap
  }

  // ---------------- fused epilogue ----------------
  const int cat = n0 >> 10;             // 0=Q, 1=K, 2=V
  const int c0 = n0 & 1023;             // col base within category
  const int nb = m0 >> 10;              // batch index
  const int l0 = m0 & 1023;             // sequence base
  const size_t hbase = ((size_t)nb * 16 + (c0 >> 6)) * 65536;
  float bs[4];
#pragma unroll
  for (int j = 0; j < 4; ++j) bs[j] = bias[n0 + wn + j * 16 + lrow];

  if (cat < 2) {
    // -------- Q / K: rope -> tile[(hh*128+lrel)][d], chunk-XOR swizzled -----
    const float scl = (cat == 0) ? 0.125f : 1.0f;
    float2 cs[4][4][2];                 // cos/sin per (i, r, p= d<32 half)
#pragma unroll
    for (int i = 0; i < 4; ++i)
#pragma unroll
      for (int r = 0; r < 4; ++r) {
        const int lg = l0 + wm + i * 16 + lgrp * 4 + r;
        cs[i][r][0] = rt[lg * 32 + lrow];
        cs[i][r][1] = rt[lg * 32 + 16 + lrow];
      }
#pragma unroll
    for (int i = 0; i < 4; ++i)
#pragma unroll
      for (int j = 0; j < 4; ++j) {
        const int hh = (wn + j * 16 + lrow) >> 6;  // head half (0/1)
        const int din = (j * 16 + lrow) & 63;      // d within head
        const float sgn = (j & 2) ? 1.0f : -1.0f;  // d<32 -> -pair
        const int p = j & 1;
#pragma unroll
        for (int r = 0; r < 4; ++r) {
          const int lrel = wm + i * 16 + lgrp * 4 + r;
          const float v = acc[i][j][r] + bs[j];
          const float vp = acc[i][j ^ 2][r] + bs[j ^ 2];
          const float2 a = cs[i][r][p];
          const float o = (v * a.x + sgn * vp * a.y) * scl;
          const int row = hh * 128 + lrel;
          smem[row * 64 + (((din >> 3) ^ (lrel & 7)) << 3) + (din & 7)] = f2bf(o);
        }
      }
    __syncthreads();
    short* dst = (cat == 0) ? qh : kh;
#pragma unroll
    for (int it = 0; it < 8; ++it) {
      const int row = it * 32 + wave * 8 + (lane >> 3);
      const int c = lane & 7;
      const int hh = row >> 7, lrel = row & 127;
      const bf16x8 v = *(const bf16x8*)&smem[row * 64 + ((c ^ (row & 7)) << 3)];
      *(bf16x8*)&dst[hbase + (size_t)hh * 65536 + (size_t)(l0 + lrel) * 64 + c * 8] = v;
    }
  } else {
    // -------- V: transpose -> tile[d][l], chunk-XOR swizzled ----------------
#pragma unroll
    for (int i = 0; i < 4; ++i)
#pragma unroll
      for (int j = 0; j < 4; ++j) {
        const int dt = wn + j * 16 + lrow;         // 0..127 (2 heads x 64 d)
        const int lb = wm + i * 16 + lgrp * 4;     // 4-aligned l base
        short4 pk;
        pk.x = f2bf(acc[i][j][0] + bs[j]); pk.y = f2bf(acc[i][j][1] + bs[j]);
        pk.z = f2bf(acc[i][j][2] + bs[j]); pk.w = f2bf(acc[i][j][3] + bs[j]);
        *(short4*)&smem[dt * 128 + ((((lb >> 3) ^ (dt & 7)) << 3) | (lb & 7))] = pk;
      }
    __syncthreads();
#pragma unroll
    for (int it = 0; it < 8; ++it) {
      const int row = it * 16 + wave * 4 + (lane >> 4);  // d_tile 0..127
      const int c = lane & 15;                           // l chunk
      const int cx = (c & 8) | ((c & 7) ^ (row & 7));
      const bf16x8 v = *(const bf16x8*)&smem[row * 128 + (cx << 3)];
      const int hh = row >> 6, d = row & 63;
      *(bf16x8*)&vt[hbase + (size_t)hh * 65536 + (size_t)d * 1024 + l0 + c * 8] = v;
    }
  }
}

// ---------------- m97-style B^T GEMM, 2-phase pipelined (proj) --------------
__global__ __launch_bounds__(256, 2) void gemm_bt(
    const short* __restrict__ A, const short* __restrict__ B,
    const float* __restrict__ bias, float* __restrict__ Cf,
    int M, int N, int K) {
  __shared__ short As[2][128 * 64];
  __shared__ short Bs[2][128 * 64];
  const int tid = threadIdx.x;
  const int lane = tid & 63, wave = tid >> 6;
  const int wm = (wave & 1) * 64, wn = (wave >> 1) * 64;
  const int lrow = lane & 15, lgrp = lane >> 4;
  const int xtiles = N >> 7;
  const int bid = blockIdx.x;
  const int cpx = gridDim.x >> 3;
  const int swz = (bid & 7) * cpx + (bid >> 3);
  const int m0 = (swz / xtiles) * 128, n0 = (swz % xtiles) * 128;
  f32x4 acc[4][4] = {};

  const int srow = tid >> 3;
  const int schunk = ((tid & 7) ^ (srow & 7)) * 8;
  const short* Ag = A + (size_t)(m0 + srow) * K + schunk;
  const short* Bg = B + (size_t)(n0 + srow) * K + schunk;

  auto stage = [&](int k0, int buf) {
#pragma unroll
    for (int r = 0; r < 4; ++r) {
      async16(Ag + (size_t)(32 * r) * K + k0, &As[buf][tid * 8 + r * 2048]);
      async16(Bg + (size_t)(32 * r) * K + k0, &Bs[buf][tid * 8 + r * 2048]);
    }
  };

  stage(0, 0);
  __syncthreads();
  const int nsteps = K >> 6;
  for (int s = 0; s < nsteps; ++s) {
    const int cur = s & 1;
    if (s + 1 < nsteps) stage((s + 1) * 64, cur ^ 1);
#pragma unroll
    for (int kk = 0; kk < 2; ++kk) {
      bf16x8 af[4], bfr[4];
#pragma unroll
      for (int i = 0; i < 4; ++i) {
        const int ra = wm + i * 16 + lrow;
        af[i] = *(const bf16x8*)&As[cur][ra * 64 + (((kk * 4 + lgrp) ^ (ra & 7)) * 8)];
        const int rb = wn + i * 16 + lrow;
        bfr[i] = *(const bf16x8*)&Bs[cur][rb * 64 + (((kk * 4 + lgrp) ^ (rb & 7)) * 8)];
      }
#pragma unroll
      for (int i = 0; i < 4; ++i)
#pragma unroll
        for (int j = 0; j < 4; ++j)
          acc[i][j] = __builtin_amdgcn_mfma_f32_16x16x32_bf16(af[i], bfr[j], acc[i][j], 0, 0, 0);
    }
    __syncthreads();
  }
#pragma unroll
  for (int j = 0; j < 4; ++j) {
    const int col = n0 + wn + j * 16 + lrow;
    const float bsv = bias[col];
#pragma unroll
    for (int i = 0; i < 4; ++i) {
      const int rb = m0 + wm + i * 16 + lgrp * 4;
#pragma unroll
      for (int r = 0; r < 4; ++r)
        Cf[(size_t)(rb + r) * N + col] = acc[i][j][r] + bsv;
    }
  }
}

// ---------------- flash attention v3: 512 thr / 8 waves, q256 per block -----
// R10: flash+out2 ~120us combined, still prefetch-latency bound (1-step
// lookahead ~350cy compute < 300-900cy load latency) with only 12 waves/CU
// and a 1.33-turn grid. Widen: 512 blocks = exactly 2/CU (1 turn), 16
// waves/CU, K/V staged once per 256 q (traffic halved, 1 async16/thread).
// Inner loop identical to the verified v2; wave owns 32 q via woff.
__global__ __launch_bounds__(512, 4) void flash_attn(
    const short* __restrict__ qh, const short* __restrict__ kh,
    const short* __restrict__ vt, short* __restrict__ attn,
    float* __restrict__ denw) {
  __shared__ short Ks[2][64 * 64];
  __shared__ short Vs[2][64 * 64];
  __shared__ short Pl[8][32 * 64];      // per-wave private P tiles (32 KB)
  const int bid = blockIdx.x;
  const int n = bid & 7;                // same n -> same XCD (L2 locality)
  const int h = (bid >> 3) & 15;
  const int q0 = (bid >> 7) * 256;      // 4 q-tiles of 256
  const int tid = threadIdx.x;
  const int wave = tid >> 6, lane = tid & 63;
  const int lrow = lane & 15, lgrp = lane >> 4;
  const int woff = wave * 32;           // 8 waves cover 256 q
  const size_t hb = (size_t)(n * 16 + h) * 65536;

  bf16x8 aq[2][2];
#pragma unroll
  for (int i = 0; i < 2; ++i)
#pragma unroll
    for (int kk = 0; kk < 2; ++kk)
      aq[i][kk] = *(const bf16x8*)(qh + hb +
          (size_t)(q0 + woff + 16 * i + lrow) * 64 + kk * 32 + lgrp * 8);

  const int srow = tid >> 3;                         // 0..63 (512 thr)
  const int schunk = ((tid & 7) ^ (srow & 7)) * 8;   // swizzled source chunk
  const short* Kg = kh + hb + (size_t)srow * 64 + schunk;
  const short* Vg = vt + hb + (size_t)srow * 1024 + schunk;
  short* Pw = &Pl[wave][0];

  f32x4 osum[2][4] = {};
  float rsum[2] = {0.f, 0.f};

  // prologue: stage tile 0 (1 async16/thread per tensor)
  async16(Kg, &Ks[0][tid * 8]);
  async16(Vg, &Vs[0][tid * 8]);
  __syncthreads();

  for (int step = 0; step < 16; ++step) {
    const int cur = step & 1;
    if (step < 15) {                    // issue NEXT tile before compute
      const int k1 = (step + 1) * 64;
      async16(Kg + (size_t)k1 * 64, &Ks[cur ^ 1][tid * 8]);
      async16(Vg + k1, &Vs[cur ^ 1][tid * 8]);
    }
    // ---- S = K @ Q (swapped): lane holds q=16i+lrow, keys 16nt+lgrp*4+r ----
    f32x4 sacc[2][4] = {};
#pragma unroll
    for (int kk = 0; kk < 2; ++kk)
#pragma unroll
      for (int nt = 0; nt < 4; ++nt) {
        const int rb = nt * 16 + lrow;
        const bf16x8 ak = *(const bf16x8*)&Ks[cur][rb * 64 + (((kk * 4 + lgrp) ^ (rb & 7)) * 8)];
#pragma unroll
        for (int i = 0; i < 2; ++i)
          sacc[i][nt] = __builtin_amdgcn_mfma_f32_16x16x32_bf16(ak, aq[i][kk], sacc[i][nt], 0, 0, 0);
      }
    // ---- exp, rowsum, packed P store (4 consecutive keys per b64) ----
#pragma unroll
    for (int i = 0; i < 2; ++i)
#pragma unroll
      for (int nt = 0; nt < 4; ++nt) {
        float e0 = __expf(sacc[i][nt][0]), e1 = __expf(sacc[i][nt][1]);
        float e2 = __expf(sacc[i][nt][2]), e3 = __expf(sacc[i][nt][3]);
        rsum[i] += (e0 + e1) + (e2 + e3);
        short4 pk = make_short4(f2bf(e0), f2bf(e1), f2bf(e2), f2bf(e3));
        const int prow = 16 * i + lrow;
        const int cb = 16 * nt + lgrp * 4;
        *(short4*)&Pw[prow * 64 + ((((cb >> 3) ^ (prow & 7))) << 3) + (cb & 7)] = pk;
      }
    // ---- PV: O += P @ V ----
#pragma unroll
    for (int kk = 0; kk < 2; ++kk) {
      bf16x8 pa[2], bv[4];
#pragma unroll
      for (int i = 0; i < 2; ++i) {
        const int ra = 16 * i + lrow;
        pa[i] = *(const bf16x8*)&Pw[ra * 64 + (((kk * 4 + lgrp) ^ (ra & 7)) * 8)];
      }
#pragma unroll
      for (int j = 0; j < 4; ++j) {
        const int rb = 16 * j + lrow;
        bv[j] = *(const bf16x8*)&Vs[cur][rb * 64 + (((kk * 4 + lgrp) ^ (rb & 7)) * 8)];
      }
#pragma unroll
      for (int i = 0; i < 2; ++i)
#pragma unroll
        for (int j = 0; j < 4; ++j)
          osum[i][j] = __builtin_amdgcn_mfma_f32_16x16x32_bf16(pa[i], bv[j], osum[i][j], 0, 0, 0);
    }
    __syncthreads();                    // drains prefetch vmcnt + buffer swap
  }
  // ---- rowsum reduce across lgrp (key partition); q = 16i+lrow ----
#pragma unroll
  for (int t = 0; t < 2; ++t) {
    rsum[t] += __shfl_xor(rsum[t], 16, 64);
    rsum[t] += __shfl_xor(rsum[t], 32, 64);
  }
  const float invq0 = 1.0f / rsum[0], invq1 = 1.0f / rsum[1];
  if (lgrp == 0) {
    denw[(size_t)(n * 16 + h) * 1024 + q0 + woff + lrow] = invq0;
    denw[(size_t)(n * 16 + h) * 1024 + q0 + woff + 16 + lrow] = invq1;
  }
  float inv8[8];
#pragma unroll
  for (int r = 0; r < 4; ++r) {
    inv8[r] = __shfl(invq0, lgrp * 4 + r, 64);
    inv8[4 + r] = __shfl(invq1, lgrp * 4 + r, 64);
  }
#pragma unroll
  for (int i = 0; i < 2; ++i)
#pragma unroll
    for (int j = 0; j < 4; ++j)
#pragma unroll
      for (int r = 0; r < 4; ++r) {
        const int row = q0 + woff + 16 * i + lgrp * 4 + r;
        attn[(size_t)(n * 1024 + row) * 1024 + h * 64 + 16 * j + lrow] =
            f2bf(osum[i][j][r] * inv8[i * 4 + r]);
      }
}

// ---------------- out2 v3: 512 thr / 8 waves, k128 per block ----------------
// block = (n, 128 q-rows, 128-key strip); waves = 4 qw x 2 kw, each owning
// 32q x 64k (acc stays 32 VGPR/thread). Q+K tiles (16KB each) staged with
// 2 async16/thread, double-buffered across heads, ONE barrier per head.
// 512 blocks = exactly 2/CU, 1 turn, 16 waves/CU.
__global__ __launch_bounds__(512, 4) void out2_kernel(
    const short* __restrict__ qh, const short* __restrict__ kh,
    const float* __restrict__ denw, float* __restrict__ out2) {
  __shared__ short Qs[2][128 * 64];
  __shared__ short Ks[2][128 * 64];
  const int bid = blockIdx.x;
  const int n = bid & 7;
  const int qt = (bid >> 3) & 7;
  const int kvs = bid >> 6;             // 0..7
  const int q0 = qt * 128, c0 = kvs * 128;
  const int tid = threadIdx.x;
  const int wave = tid >> 6, lane = tid & 63;
  const int lrow = lane & 15, lgrp = lane >> 4;
  const int qw = wave & 3, kw = wave >> 2;
  const int woff = qw * 32;

  const int srow = tid >> 3;            // 0..63
  const int schunk = ((tid & 7) ^ (srow & 7)) * 8;

  f32x4 acc[2][4] = {};

  auto stage = [&](int hh, int buf) {
    const size_t hb = (size_t)(n * 16 + hh) * 65536;
#pragma unroll
    for (int r = 0; r < 2; ++r) {
      async16(qh + hb + (size_t)(q0 + 64 * r + srow) * 64 + schunk,
              &Qs[buf][tid * 8 + r * 4096]);
      async16(kh + hb + (size_t)(c0 + 64 * r + srow) * 64 + schunk,
              &Ks[buf][tid * 8 + r * 4096]);
    }
  };

  stage(0, 0);
  __syncthreads();
  for (int h = 0; h < 16; ++h) {
    const int cur = h & 1;
    float invv[8];
#pragma unroll
    for (int i = 0; i < 2; ++i)
#pragma unroll
      for (int r = 0; r < 4; ++r)
        invv[i * 4 + r] =
            denw[(size_t)(n * 16 + h) * 1024 + q0 + woff + 16 * i + lgrp * 4 + r];
    if (h < 15) stage(h + 1, cur ^ 1);
    bf16x8 aq[2][2];
#pragma unroll
    for (int i = 0; i < 2; ++i)
#pragma unroll
      for (int kk = 0; kk < 2; ++kk) {
        const int ra = woff + 16 * i + lrow;
        aq[i][kk] = *(const bf16x8*)&Qs[cur][ra * 64 + (((kk * 4 + lgrp) ^ (ra & 7)) * 8)];
      }
    f32x4 sacc[2][4] = {};
#pragma unroll
    for (int kk = 0; kk < 2; ++kk)
#pragma unroll
      for (int nt = 0; nt < 4; ++nt) {
        const int rb = kw * 64 + nt * 16 + lrow;
        const bf16x8 bk = *(const bf16x8*)&Ks[cur][rb * 64 + (((kk * 4 + lgrp) ^ (rb & 7)) * 8)];
#pragma unroll
        for (int i = 0; i < 2; ++i)
          sacc[i][nt] = __builtin_amdgcn_mfma_f32_16x16x32_bf16(aq[i][kk], bk, sacc[i][nt], 0, 0, 0);
      }
#pragma unroll
    for (int i = 0; i < 2; ++i)
#pragma unroll
      for (int nt = 0; nt < 4; ++nt)
#pragma unroll
        for (int r = 0; r < 4; ++r)
          acc[i][nt][r] += __expf(sacc[i][nt][r]) * invv[i * 4 + r];
    __syncthreads();
  }
#pragma unroll
  for (int i = 0; i < 2; ++i)
#pragma unroll
    for (int nt = 0; nt < 4; ++nt)
#pragma unroll
      for (int r = 0; r < 4; ++r) {
        const int row = q0 + woff + 16 * i + lgrp * 4 + r;
        out2[(size_t)(n * 1024 + row) * 1024 + c0 + kw * 64 + nt * 16 + lrow] =
            acc[i][nt][r] * 0.0625f;
      }
}

extern "C" void kernel_launch(void* const* d_in, const int* in_sizes, int n_in,
                              void* d_out, int out_size, void* d_ws, size_t ws_size,
                              hipStream_t stream) {
  const float* x  = (const float*)d_in[0];   // (8,1024,1024)
  const float* Wi = (const float*)d_in[1];   // (3072,1024)
  const float* bi = (const float*)d_in[2];   // (3072,)
  const float* Wo = (const float*)d_in[3];   // (1024,1024)
  const float* bo = (const float*)d_in[4];   // (1024,)
  float* out  = (float*)d_out;                       // (8,1024,1024)
  float* out2 = out + (size_t)8 * 1024 * 1024;       // (8,1024,1024) mean attn

  char* p = (char*)d_ws;
  short* xb  = (short*)p; p += (size_t)8388608 * 2;   // x bf16 (reused as attn later)
  short* wb  = (short*)p; p += (size_t)3145728 * 2;   // W_in bf16
  short* wob = (short*)p; p += (size_t)1048576 * 2;   // W_out bf16
  short* qh  = (short*)p; p += (size_t)8388608 * 2;   // (n,h,l,d) bf16, pre-scaled
  short* kh  = (short*)p; p += (size_t)8388608 * 2;   // (n,h,l,d) bf16
  short* vt  = (short*)p; p += (size_t)8388608 * 2;   // (n,h,d,l) bf16
  float* denw = (float*)p; p += (size_t)131072 * 4;   // inv softmax denominators
  float2* ropet = (float2*)p; p += (size_t)32768 * 8; // rope cos/sin table
  short* attn = xb;  // xb dead after gemm_qkv

  convert3<<<2048, 256, 0, stream>>>(x, xb, 8388608 / 4, Wi, wb, 3145728 / 4,
                                     Wo, wob, 1048576 / 4, ropet);
  gemm_qkv<<<1536, 256, 0, stream>>>(xb, wb, bi, ropet, qh, kh, vt);
  flash_attn<<<512, 512, 0, stream>>>(qh, kh, vt, attn, denw);
  out2_kernel<<<512, 512, 0, stream>>>(qh, kh, denw, out2);
  gemm_bt<<<512, 256, 0, stream>>>(attn, wob, bo, out, 8192, 1024, 1024);
}

// Round 11
// 250.873 us; speedup vs baseline: 1.2034x; 1.0559x over previous
//
#include <hip/hip_runtime.h>
#include <hip/hip_bf16.h>
#include <math.h>

// Problem constants: N=8, L=1024, D=1024, H=16, hd=64, SCALE=0.125
typedef short bf16x8 __attribute__((ext_vector_type(8)));
typedef float f32x4 __attribute__((ext_vector_type(4)));

__device__ __forceinline__ short f2bf(float f) {
  unsigned u = __float_as_uint(f);
  u += 0x7fffu + ((u >> 16) & 1u);          // RNE
  return (short)(u >> 16);
}
__device__ __forceinline__ float bf2f(short h) {
  return __uint_as_float(((unsigned)(unsigned short)h) << 16);
}

typedef __attribute__((address_space(1))) void glob_void;
typedef __attribute__((address_space(3))) void lds_void;
// async global->LDS, 16B per lane; LDS dest = wave-uniform base + lane*16
__device__ __forceinline__ void async16(const void* g, void* l) {
  __builtin_amdgcn_global_load_lds((glob_void*)(uintptr_t)g,
                                   (lds_void*)(unsigned int)(uintptr_t)l,
                                   16, 0, 0);
}

// -------- fp32 -> bf16 conversion of x, W_in, W_out + RoPE cos/sin table ----
__global__ void convert3(const float* __restrict__ a, short* __restrict__ ab, int na4,
                         const float* __restrict__ b, short* __restrict__ bb, int nb4,
                         const float* __restrict__ c, short* __restrict__ cb, int nc4,
                         float2* __restrict__ rt) {
  int tid = blockIdx.x * blockDim.x + threadIdx.x;
  int stride = gridDim.x * blockDim.x;
  for (int i = tid; i < na4; i += stride) {
    float4 v = ((const float4*)a)[i];
    ((short4*)ab)[i] = make_short4(f2bf(v.x), f2bf(v.y), f2bf(v.z), f2bf(v.w));
  }
  for (int i = tid; i < nb4; i += stride) {
    float4 v = ((const float4*)b)[i];
    ((short4*)bb)[i] = make_short4(f2bf(v.x), f2bf(v.y), f2bf(v.z), f2bf(v.w));
  }
  for (int i = tid; i < nc4; i += stride) {
    float4 v = ((const float4*)c)[i];
    ((short4*)cb)[i] = make_short4(f2bf(v.x), f2bf(v.y), f2bf(v.z), f2bf(v.w));
  }
  // RoPE table: rt[l*32+dj] = (cos, sin)(l * 10000^(-dj/32)), l<1024, dj<32
  for (int i = tid; i < 32768; i += stride) {
    const int l = i >> 5, dj = i & 31;
    float s, cc;
    sincosf((float)l * exp2f(-0.4152410118609203f * (float)dj), &s, &cc);
    rt[i] = make_float2(cc, s);
  }
}

// ---------------- QKV GEMM + fused RoPE/head-split/V-transpose --------------
// C = x @ W_in^T + b_in, then per output category:
//   Q cols (0-1023):    rope (table) * 0.125 -> qh (n,h,l,d)
//   K cols (1024-2047): rope (table)          -> kh (n,h,l,d)
//   V cols (2048-3071): transpose             -> vt (n,h,d,l)
// Rope pairing d<->d+-32 is IN-THREAD: acc[i][j] pairs acc[i][j^2] (cols +-32).
// Epilogue bounces through the dead 64KB staging LDS with chunk-XOR swizzle
// then writes fully-coalesced 1KB/wave stores. (R9: 67.5us, 32% MfmaUtil.)
__global__ __launch_bounds__(256, 2) void gemm_qkv(
    const short* __restrict__ A, const short* __restrict__ B,
    const float* __restrict__ bias, const float2* __restrict__ rt,
    short* __restrict__ qh, short* __restrict__ kh, short* __restrict__ vt) {
  __shared__ short smem[32768];         // main loop: As/Bs dbuf; epilogue: tile
  const int K = 1024, xtiles = 24;
  const int tid = threadIdx.x;
  const int lane = tid & 63, wave = tid >> 6;
  const int wm = (wave & 1) * 64, wn = (wave >> 1) * 64;
  const int lrow = lane & 15, lgrp = lane >> 4;
  const int bid = blockIdx.x;
  const int cpx = gridDim.x >> 3;       // XCD-chunked swizzle (nwg%8==0)
  const int swz = (bid & 7) * cpx + (bid >> 3);
  const int m0 = (swz / xtiles) * 128, n0 = (swz % xtiles) * 128;
  f32x4 acc[4][4] = {};

  const int srow = tid >> 3;                         // 0..31
  const int schunk = ((tid & 7) ^ (srow & 7)) * 8;   // swizzled source chunk
  const short* Ag = A + (size_t)(m0 + srow) * K + schunk;
  const short* Bg = B + (size_t)(n0 + srow) * K + schunk;
  short* As = smem;                     // [2][8192]
  short* Bs = smem + 16384;             // [2][8192]

  auto stage = [&](int k0, int buf) {
#pragma unroll
    for (int r = 0; r < 4; ++r) {
      async16(Ag + (size_t)(32 * r) * K + k0, &As[buf * 8192 + tid * 8 + r * 2048]);
      async16(Bg + (size_t)(32 * r) * K + k0, &Bs[buf * 8192 + tid * 8 + r * 2048]);
    }
  };

  stage(0, 0);
  __syncthreads();
  for (int s = 0; s < 16; ++s) {
    const int cur = s & 1;
    if (s < 15) stage((s + 1) * 64, cur ^ 1);  // prefetch before compute
#pragma unroll
    for (int kk = 0; kk < 2; ++kk) {
      bf16x8 af[4], bfr[4];
#pragma unroll
      for (int i = 0; i < 4; ++i) {
        const int ra = wm + i * 16 + lrow;
        af[i] = *(const bf16x8*)&As[cur * 8192 + ra * 64 + (((kk * 4 + lgrp) ^ (ra & 7)) * 8)];
        const int rb = wn + i * 16 + lrow;
        bfr[i] = *(const bf16x8*)&Bs[cur * 8192 + rb * 64 + (((kk * 4 + lgrp) ^ (rb & 7)) * 8)];
      }
#pragma unroll
      for (int i = 0; i < 4; ++i)
#pragma unroll
        for (int j = 0; j < 4; ++j)
          acc[i][j] = __builtin_amdgcn_mfma_f32_16x16x32_bf16(af[i], bfr[j], acc[i][j], 0, 0, 0);
    }
    __syncthreads();                    // drains prefetch vmcnt + buffer swap
  }

  // ---------------- fused epilogue ----------------
  const int cat = n0 >> 10;             // 0=Q, 1=K, 2=V
  const int c0 = n0 & 1023;             // col base within category
  const int nb = m0 >> 10;              // batch index
  const int l0 = m0 & 1023;             // sequence base
  const size_t hbase = ((size_t)nb * 16 + (c0 >> 6)) * 65536;
  float bs[4];
#pragma unroll
  for (int j = 0; j < 4; ++j) bs[j] = bias[n0 + wn + j * 16 + lrow];

  if (cat < 2) {
    // -------- Q / K: rope -> tile[(hh*128+lrel)][d], chunk-XOR swizzled -----
    const float scl = (cat == 0) ? 0.125f : 1.0f;
    float2 cs[4][4][2];                 // cos/sin per (i, r, p= d<32 half)
#pragma unroll
    for (int i = 0; i < 4; ++i)
#pragma unroll
      for (int r = 0; r < 4; ++r) {
        const int lg = l0 + wm + i * 16 + lgrp * 4 + r;
        cs[i][r][0] = rt[lg * 32 + lrow];
        cs[i][r][1] = rt[lg * 32 + 16 + lrow];
      }
#pragma unroll
    for (int i = 0; i < 4; ++i)
#pragma unroll
      for (int j = 0; j < 4; ++j) {
        const int hh = (wn + j * 16 + lrow) >> 6;  // head half (0/1)
        const int din = (j * 16 + lrow) & 63;      // d within head
        const float sgn = (j & 2) ? 1.0f : -1.0f;  // d<32 -> -pair
        const int p = j & 1;
#pragma unroll
        for (int r = 0; r < 4; ++r) {
          const int lrel = wm + i * 16 + lgrp * 4 + r;
          const float v = acc[i][j][r] + bs[j];
          const float vp = acc[i][j ^ 2][r] + bs[j ^ 2];
          const float2 a = cs[i][r][p];
          const float o = (v * a.x + sgn * vp * a.y) * scl;
          const int row = hh * 128 + lrel;
          smem[row * 64 + (((din >> 3) ^ (lrel & 7)) << 3) + (din & 7)] = f2bf(o);
        }
      }
    __syncthreads();
    short* dst = (cat == 0) ? qh : kh;
#pragma unroll
    for (int it = 0; it < 8; ++it) {
      const int row = it * 32 + wave * 8 + (lane >> 3);
      const int c = lane & 7;
      const int hh = row >> 7, lrel = row & 127;
      const bf16x8 v = *(const bf16x8*)&smem[row * 64 + ((c ^ (row & 7)) << 3)];
      *(bf16x8*)&dst[hbase + (size_t)hh * 65536 + (size_t)(l0 + lrel) * 64 + c * 8] = v;
    }
  } else {
    // -------- V: transpose -> tile[d][l], chunk-XOR swizzled ----------------
#pragma unroll
    for (int i = 0; i < 4; ++i)
#pragma unroll
      for (int j = 0; j < 4; ++j) {
        const int dt = wn + j * 16 + lrow;         // 0..127 (2 heads x 64 d)
        const int lb = wm + i * 16 + lgrp * 4;     // 4-aligned l base
        short4 pk;
        pk.x = f2bf(acc[i][j][0] + bs[j]); pk.y = f2bf(acc[i][j][1] + bs[j]);
        pk.z = f2bf(acc[i][j][2] + bs[j]); pk.w = f2bf(acc[i][j][3] + bs[j]);
        *(short4*)&smem[dt * 128 + ((((lb >> 3) ^ (dt & 7)) << 3) | (lb & 7))] = pk;
      }
    __syncthreads();
#pragma unroll
    for (int it = 0; it < 8; ++it) {
      const int row = it * 16 + wave * 4 + (lane >> 4);  // d_tile 0..127
      const int c = lane & 15;                           // l chunk
      const int cx = (c & 8) | ((c & 7) ^ (row & 7));
      const bf16x8 v = *(const bf16x8*)&smem[row * 128 + (cx << 3)];
      const int hh = row >> 6, d = row & 63;
      *(bf16x8*)&vt[hbase + (size_t)hh * 65536 + (size_t)d * 1024 + l0 + c * 8] = v;
    }
  }
}

// ---------------- m97-style B^T GEMM, 2-phase pipelined (proj) --------------
__global__ __launch_bounds__(256, 2) void gemm_bt(
    const short* __restrict__ A, const short* __restrict__ B,
    const float* __restrict__ bias, float* __restrict__ Cf,
    int M, int N, int K) {
  __shared__ short As[2][128 * 64];
  __shared__ short Bs[2][128 * 64];
  const int tid = threadIdx.x;
  const int lane = tid & 63, wave = tid >> 6;
  const int wm = (wave & 1) * 64, wn = (wave >> 1) * 64;
  const int lrow = lane & 15, lgrp = lane >> 4;
  const int xtiles = N >> 7;
  const int bid = blockIdx.x;
  const int cpx = gridDim.x >> 3;
  const int swz = (bid & 7) * cpx + (bid >> 3);
  const int m0 = (swz / xtiles) * 128, n0 = (swz % xtiles) * 128;
  f32x4 acc[4][4] = {};

  const int srow = tid >> 3;
  const int schunk = ((tid & 7) ^ (srow & 7)) * 8;
  const short* Ag = A + (size_t)(m0 + srow) * K + schunk;
  const short* Bg = B + (size_t)(n0 + srow) * K + schunk;

  auto stage = [&](int k0, int buf) {
#pragma unroll
    for (int r = 0; r < 4; ++r) {
      async16(Ag + (size_t)(32 * r) * K + k0, &As[buf][tid * 8 + r * 2048]);
      async16(Bg + (size_t)(32 * r) * K + k0, &Bs[buf][tid * 8 + r * 2048]);
    }
  };

  stage(0, 0);
  __syncthreads();
  const int nsteps = K >> 6;
  for (int s = 0; s < nsteps; ++s) {
    const int cur = s & 1;
    if (s + 1 < nsteps) stage((s + 1) * 64, cur ^ 1);
#pragma unroll
    for (int kk = 0; kk < 2; ++kk) {
      bf16x8 af[4], bfr[4];
#pragma unroll
      for (int i = 0; i < 4; ++i) {
        const int ra = wm + i * 16 + lrow;
        af[i] = *(const bf16x8*)&As[cur][ra * 64 + (((kk * 4 + lgrp) ^ (ra & 7)) * 8)];
        const int rb = wn + i * 16 + lrow;
        bfr[i] = *(const bf16x8*)&Bs[cur][rb * 64 + (((kk * 4 + lgrp) ^ (rb & 7)) * 8)];
      }
#pragma unroll
      for (int i = 0; i < 4; ++i)
#pragma unroll
        for (int j = 0; j < 4; ++j)
          acc[i][j] = __builtin_amdgcn_mfma_f32_16x16x32_bf16(af[i], bfr[j], acc[i][j], 0, 0, 0);
    }
    __syncthreads();
  }
#pragma unroll
  for (int j = 0; j < 4; ++j) {
    const int col = n0 + wn + j * 16 + lrow;
    const float bsv = bias[col];
#pragma unroll
    for (int i = 0; i < 4; ++i) {
      const int rb = m0 + wm + i * 16 + lgrp * 4;
#pragma unroll
      for (int r = 0; r < 4; ++r)
        Cf[(size_t)(rb + r) * N + col] = acc[i][j][r] + bsv;
    }
  }
}

// ---------------- flash attention v4: 3-buffer counted-vmcnt pipeline -------
// R11: v3's per-step __syncthreads force-drained the t+1 prefetch (implicit
// vmcnt(0)) after only ~400cy of compute cover -- the T4 drain stall. Fix:
// 3 K/V buffers, 2-deep prefetch, raw s_barrier + counted `s_waitcnt
// vmcnt(2)` (each stage = 2 loads/thread; issued through stage s+1 at iter-s
// top, so vmcnt(2) completes exactly stage s while s+1 flies). stage(s+2) is
// issued AFTER the barrier, so its buffer ((s+2)%3 == (s-1)%3) is only
// overwritten once every wave finished compute(s-1). One barrier per step.
// T5 setprio(1) wraps the MFMA clusters. LDS 80KB -> 2 blocks/CU.
__global__ __launch_bounds__(512, 4) void flash_attn(
    const short* __restrict__ qh, const short* __restrict__ kh,
    const short* __restrict__ vt, short* __restrict__ attn,
    float* __restrict__ denw) {
  __shared__ short Ks[3][64 * 64];
  __shared__ short Vs[3][64 * 64];
  __shared__ short Pl[8][32 * 64];      // per-wave private P tiles (32 KB)
  const int bid = blockIdx.x;
  const int n = bid & 7;                // same n -> same XCD (L2 locality)
  const int h = (bid >> 3) & 15;
  const int q0 = (bid >> 7) * 256;      // 4 q-tiles of 256
  const int tid = threadIdx.x;
  const int wave = tid >> 6, lane = tid & 63;
  const int lrow = lane & 15, lgrp = lane >> 4;
  const int woff = wave * 32;           // 8 waves cover 256 q
  const size_t hb = (size_t)(n * 16 + h) * 65536;

  bf16x8 aq[2][2];
#pragma unroll
  for (int i = 0; i < 2; ++i)
#pragma unroll
    for (int kk = 0; kk < 2; ++kk)
      aq[i][kk] = *(const bf16x8*)(qh + hb +
          (size_t)(q0 + woff + 16 * i + lrow) * 64 + kk * 32 + lgrp * 8);

  const int srow = tid >> 3;                         // 0..63 (512 thr)
  const int schunk = ((tid & 7) ^ (srow & 7)) * 8;   // swizzled source chunk
  const short* Kg = kh + hb + (size_t)srow * 64 + schunk;
  const short* Vg = vt + hb + (size_t)srow * 1024 + schunk;
  short* Pw = &Pl[wave][0];

  f32x4 osum[2][4] = {};
  float rsum[2] = {0.f, 0.f};

  // prologue: stage tiles 0 and 1 (per-thread FIFO: K0,V0,K1,V1)
  async16(Kg, &Ks[0][tid * 8]);
  async16(Vg, &Vs[0][tid * 8]);
  async16(Kg + (size_t)64 * 64, &Ks[1][tid * 8]);
  async16(Vg + 64, &Vs[1][tid * 8]);

  for (int step = 0; step < 16; ++step) {
    const int cur = step % 3;
    if (step < 15) asm volatile("s_waitcnt vmcnt(2)" ::: "memory");
    else           asm volatile("s_waitcnt vmcnt(0)" ::: "memory");
    __builtin_amdgcn_s_barrier();
    asm volatile("" ::: "memory");      // fence: keep this step's LDS reads below barrier
    if (step < 14) {                    // 2-deep prefetch, issued post-barrier
      const int k2 = (step + 2) * 64;
      const int nb3 = (step + 2) % 3;
      async16(Kg + (size_t)k2 * 64, &Ks[nb3][tid * 8]);
      async16(Vg + k2, &Vs[nb3][tid * 8]);
    }
    // ---- S = K @ Q (swapped): lane holds q=16i+lrow, keys 16nt+lgrp*4+r ----
    f32x4 sacc[2][4] = {};
    __builtin_amdgcn_s_setprio(1);
#pragma unroll
    for (int kk = 0; kk < 2; ++kk)
#pragma unroll
      for (int nt = 0; nt < 4; ++nt) {
        const int rb = nt * 16 + lrow;
        const bf16x8 ak = *(const bf16x8*)&Ks[cur][rb * 64 + (((kk * 4 + lgrp) ^ (rb & 7)) * 8)];
#pragma unroll
        for (int i = 0; i < 2; ++i)
          sacc[i][nt] = __builtin_amdgcn_mfma_f32_16x16x32_bf16(ak, aq[i][kk], sacc[i][nt], 0, 0, 0);
      }
    __builtin_amdgcn_s_setprio(0);
    // ---- exp, rowsum, packed P store (4 consecutive keys per b64) ----
#pragma unroll
    for (int i = 0; i < 2; ++i)
#pragma unroll
      for (int nt = 0; nt < 4; ++nt) {
        float e0 = __expf(sacc[i][nt][0]), e1 = __expf(sacc[i][nt][1]);
        float e2 = __expf(sacc[i][nt][2]), e3 = __expf(sacc[i][nt][3]);
        rsum[i] += (e0 + e1) + (e2 + e3);
        short4 pk = make_short4(f2bf(e0), f2bf(e1), f2bf(e2), f2bf(e3));
        const int prow = 16 * i + lrow;
        const int cb = 16 * nt + lgrp * 4;
        *(short4*)&Pw[prow * 64 + ((((cb >> 3) ^ (prow & 7))) << 3) + (cb & 7)] = pk;
      }
    // ---- PV: O += P @ V ----
    __builtin_amdgcn_s_setprio(1);
#pragma unroll
    for (int kk = 0; kk < 2; ++kk) {
      bf16x8 pa[2], bv[4];
#pragma unroll
      for (int i = 0; i < 2; ++i) {
        const int ra = 16 * i + lrow;
        pa[i] = *(const bf16x8*)&Pw[ra * 64 + (((kk * 4 + lgrp) ^ (ra & 7)) * 8)];
      }
#pragma unroll
      for (int j = 0; j < 4; ++j) {
        const int rb = 16 * j + lrow;
        bv[j] = *(const bf16x8*)&Vs[cur][rb * 64 + (((kk * 4 + lgrp) ^ (rb & 7)) * 8)];
      }
#pragma unroll
      for (int i = 0; i < 2; ++i)
#pragma unroll
        for (int j = 0; j < 4; ++j)
          osum[i][j] = __builtin_amdgcn_mfma_f32_16x16x32_bf16(pa[i], bv[j], osum[i][j], 0, 0, 0);
    }
    __builtin_amdgcn_s_setprio(0);
  }
  // ---- rowsum reduce across lgrp (key partition); q = 16i+lrow ----
#pragma unroll
  for (int t = 0; t < 2; ++t) {
    rsum[t] += __shfl_xor(rsum[t], 16, 64);
    rsum[t] += __shfl_xor(rsum[t], 32, 64);
  }
  const float invq0 = 1.0f / rsum[0], invq1 = 1.0f / rsum[1];
  if (lgrp == 0) {
    denw[(size_t)(n * 16 + h) * 1024 + q0 + woff + lrow] = invq0;
    denw[(size_t)(n * 16 + h) * 1024 + q0 + woff + 16 + lrow] = invq1;
  }
  float inv8[8];
#pragma unroll
  for (int r = 0; r < 4; ++r) {
    inv8[r] = __shfl(invq0, lgrp * 4 + r, 64);
    inv8[4 + r] = __shfl(invq1, lgrp * 4 + r, 64);
  }
#pragma unroll
  for (int i = 0; i < 2; ++i)
#pragma unroll
    for (int j = 0; j < 4; ++j)
#pragma unroll
      for (int r = 0; r < 4; ++r) {
        const int row = q0 + woff + 16 * i + lgrp * 4 + r;
        attn[(size_t)(n * 1024 + row) * 1024 + h * 64 + 16 * j + lrow] =
            f2bf(osum[i][j][r] * inv8[i * 4 + r]);
      }
}

// ---------------- out2 v3: 512 thr / 8 waves, k128 per block ----------------
// block = (n, 128 q-rows, 128-key strip); waves = 4 qw x 2 kw, each owning
// 32q x 64k. Q+K tiles double-buffered across heads, ONE barrier per head.
// (2-buf counted-vmcnt gains nothing: the newest staged tile is the one
// consumed next; 3-buf needs 96KB -> occupancy loss. Only T5 added.)
__global__ __launch_bounds__(512, 4) void out2_kernel(
    const short* __restrict__ qh, const short* __restrict__ kh,
    const float* __restrict__ denw, float* __restrict__ out2) {
  __shared__ short Qs[2][128 * 64];
  __shared__ short Ks[2][128 * 64];
  const int bid = blockIdx.x;
  const int n = bid & 7;
  const int qt = (bid >> 3) & 7;
  const int kvs = bid >> 6;             // 0..7
  const int q0 = qt * 128, c0 = kvs * 128;
  const int tid = threadIdx.x;
  const int wave = tid >> 6, lane = tid & 63;
  const int lrow = lane & 15, lgrp = lane >> 4;
  const int qw = wave & 3, kw = wave >> 2;
  const int woff = qw * 32;

  const int srow = tid >> 3;            // 0..63
  const int schunk = ((tid & 7) ^ (srow & 7)) * 8;

  f32x4 acc[2][4] = {};

  auto stage = [&](int hh, int buf) {
    const size_t hb = (size_t)(n * 16 + hh) * 65536;
#pragma unroll
    for (int r = 0; r < 2; ++r) {
      async16(qh + hb + (size_t)(q0 + 64 * r + srow) * 64 + schunk,
              &Qs[buf][tid * 8 + r * 4096]);
      async16(kh + hb + (size_t)(c0 + 64 * r + srow) * 64 + schunk,
              &Ks[buf][tid * 8 + r * 4096]);
    }
  };

  stage(0, 0);
  __syncthreads();
  for (int h = 0; h < 16; ++h) {
    const int cur = h & 1;
    float invv[8];
#pragma unroll
    for (int i = 0; i < 2; ++i)
#pragma unroll
      for (int r = 0; r < 4; ++r)
        invv[i * 4 + r] =
            denw[(size_t)(n * 16 + h) * 1024 + q0 + woff + 16 * i + lgrp * 4 + r];
    if (h < 15) stage(h + 1, cur ^ 1);
    bf16x8 aq[2][2];
#pragma unroll
    for (int i = 0; i < 2; ++i)
#pragma unroll
      for (int kk = 0; kk < 2; ++kk) {
        const int ra = woff + 16 * i + lrow;
        aq[i][kk] = *(const bf16x8*)&Qs[cur][ra * 64 + (((kk * 4 + lgrp) ^ (ra & 7)) * 8)];
      }
    f32x4 sacc[2][4] = {};
    __builtin_amdgcn_s_setprio(1);
#pragma unroll
    for (int kk = 0; kk < 2; ++kk)
#pragma unroll
      for (int nt = 0; nt < 4; ++nt) {
        const int rb = kw * 64 + nt * 16 + lrow;
        const bf16x8 bk = *(const bf16x8*)&Ks[cur][rb * 64 + (((kk * 4 + lgrp) ^ (rb & 7)) * 8)];
#pragma unroll
        for (int i = 0; i < 2; ++i)
          sacc[i][nt] = __builtin_amdgcn_mfma_f32_16x16x32_bf16(aq[i][kk], bk, sacc[i][nt], 0, 0, 0);
      }
    __builtin_amdgcn_s_setprio(0);
#pragma unroll
    for (int i = 0; i < 2; ++i)
#pragma unroll
      for (int nt = 0; nt < 4; ++nt)
#pragma unroll
        for (int r = 0; r < 4; ++r)
          acc[i][nt][r] += __expf(sacc[i][nt][r]) * invv[i * 4 + r];
    __syncthreads();
  }
#pragma unroll
  for (int i = 0; i < 2; ++i)
#pragma unroll
    for (int nt = 0; nt < 4; ++nt)
#pragma unroll
      for (int r = 0; r < 4; ++r) {
        const int row = q0 + woff + 16 * i + lgrp * 4 + r;
        out2[(size_t)(n * 1024 + row) * 1024 + c0 + kw * 64 + nt * 16 + lrow] =
            acc[i][nt][r] * 0.0625f;
      }
}

extern "C" void kernel_launch(void* const* d_in, const int* in_sizes, int n_in,
                              void* d_out, int out_size, void* d_ws, size_t ws_size,
                              hipStream_t stream) {
  const float* x  = (const float*)d_in[0];   // (8,1024,1024)
  const float* Wi = (const float*)d_in[1];   // (3072,1024)
  const float* bi = (const float*)d_in[2];   // (3072,)
  const float* Wo = (const float*)d_in[3];   // (1024,1024)
  const float* bo = (const float*)d_in[4];   // (1024,)
  float* out  = (float*)d_out;                       // (8,1024,1024)
  float* out2 = out + (size_t)8 * 1024 * 1024;       // (8,1024,1024) mean attn

  char* p = (char*)d_ws;
  short* xb  = (short*)p; p += (size_t)8388608 * 2;   // x bf16 (reused as attn later)
  short* wb  = (short*)p; p += (size_t)3145728 * 2;   // W_in bf16
  short* wob = (short*)p; p += (size_t)1048576 * 2;   // W_out bf16
  short* qh  = (short*)p; p += (size_t)8388608 * 2;   // (n,h,l,d) bf16, pre-scaled
  short* kh  = (short*)p; p += (size_t)8388608 * 2;   // (n,h,l,d) bf16
  short* vt  = (short*)p; p += (size_t)8388608 * 2;   // (n,h,d,l) bf16
  float* denw = (float*)p; p += (size_t)131072 * 4;   // inv softmax denominators
  float2* ropet = (float2*)p; p += (size_t)32768 * 8; // rope cos/sin table
  short* attn = xb;  // xb dead after gemm_qkv

  convert3<<<2048, 256, 0, stream>>>(x, xb, 8388608 / 4, Wi, wb, 3145728 / 4,
                                     Wo, wob, 1048576 / 4, ropet);
  gemm_qkv<<<1536, 256, 0, stream>>>(xb, wb, bi, ropet, qh, kh, vt);
  flash_attn<<<512, 512, 0, stream>>>(qh, kh, vt, attn, denw);
  out2_kernel<<<512, 512, 0, stream>>>(qh, kh, denw, out2);
  gemm_bt<<<512, 256, 0, stream>>>(attn, wob, bo, out, 8192, 1024, 1024);
}